// Round 6
// baseline (911.100 us; speedup 1.0000x reference)
//
#include <hip/hip_runtime.h>
#include <hip/hip_cooperative_groups.h>
#include <math.h>

namespace cg = cooperative_groups;

#define GRID  512          // 2 blocks/CU x 256 CUs — guaranteed co-residency
#define NEMB  200000
#define MM    200
#define KTOP  32
#define BB    1024
#define FEW   5

__device__ __forceinline__ float sigf(float x) { return 1.0f / (1.0f + expf(-x)); }

struct KParams {
    const int *query, *support, *qlc, *qrc, *slc, *srrc;
    const float *emb;
    const float *gcn_W, *gcn_bias, *gcn_b;
    const float *w1, *b1, *w2, *b2;
    const float *lng, *lnb;
    const float *Wih, *Whh, *bih, *bhh;
    float *out;
    float *qn2, *h1q, *yq, *qg2, *sg0, *sgn, *gates, *c1, *hr, *sims;
};

// 64x64 tile fp32 GEMM phase: C = A[M,K] @ W[N',K]^T (+b1)(+b2)(+add)(relu)
// GMAP: output col n -> W row ((n>>8)<<9)|(n&255) (LSTM gate compaction).
template <bool RELU_STORE, bool GMAP>
__device__ void gemm64(const float* __restrict__ A, const float* __restrict__ W,
                       const float* __restrict__ bias1, const float* __restrict__ bias2,
                       const float* __restrict__ add, float* __restrict__ C,
                       int Mt, int Nt, int Kt,
                       float (&As)[16][68], float (&Ws)[16][68])
{
    const int ntx = Nt >> 6;
    const int tile = blockIdx.x;
    if (tile >= (Mt >> 6) * ntx) return;
    const int t  = threadIdx.x;
    const int bm = (tile / ntx) * 64, bn = (tile % ntx) * 64;
    const int tx = t & 15, ty = t >> 4;
    const int lrow = t >> 2, lk4 = (t & 3) * 4;

    int wrow = bn + lrow;
    if (GMAP) wrow = ((wrow >> 8) << 9) | (wrow & 255);
    const float* Ap = A + (size_t)(bm + lrow) * Kt + lk4;
    const float* Wp = W + (size_t)wrow * Kt + lk4;

    float acc[4][4] = {};
    for (int k0 = 0; k0 < Kt; k0 += 16) {
        float4 av = *(const float4*)(Ap + k0);
        float4 wv = *(const float4*)(Wp + k0);
        __syncthreads();
        As[lk4 + 0][lrow] = av.x; As[lk4 + 1][lrow] = av.y;
        As[lk4 + 2][lrow] = av.z; As[lk4 + 3][lrow] = av.w;
        Ws[lk4 + 0][lrow] = wv.x; Ws[lk4 + 1][lrow] = wv.y;
        Ws[lk4 + 2][lrow] = wv.z; Ws[lk4 + 3][lrow] = wv.w;
        __syncthreads();
        #pragma unroll
        for (int kk = 0; kk < 16; ++kk) {
            float4 a = *(const float4*)&As[kk][ty * 4];
            float4 b = *(const float4*)&Ws[kk][tx * 4];
            acc[0][0] += a.x * b.x; acc[0][1] += a.x * b.y; acc[0][2] += a.x * b.z; acc[0][3] += a.x * b.w;
            acc[1][0] += a.y * b.x; acc[1][1] += a.y * b.y; acc[1][2] += a.y * b.z; acc[1][3] += a.y * b.w;
            acc[2][0] += a.z * b.x; acc[2][1] += a.z * b.y; acc[2][2] += a.z * b.z; acc[2][3] += a.z * b.w;
            acc[3][0] += a.w * b.x; acc[3][1] += a.w * b.y; acc[3][2] += a.w * b.z; acc[3][3] += a.w * b.w;
        }
    }

    const int n0 = bn + tx * 4;
    float4 bv = make_float4(0.f, 0.f, 0.f, 0.f);
    if (bias1) {
        int nb = GMAP ? (((n0 >> 8) << 9) | (n0 & 255)) : n0;
        bv = *(const float4*)(bias1 + nb);
        if (bias2) {
            float4 b2v = *(const float4*)(bias2 + nb);
            bv.x += b2v.x; bv.y += b2v.y; bv.z += b2v.z; bv.w += b2v.w;
        }
    }
    #pragma unroll
    for (int i = 0; i < 4; ++i) {
        int m = bm + ty * 4 + i;
        float4 v = make_float4(acc[i][0] + bv.x, acc[i][1] + bv.y,
                               acc[i][2] + bv.z, acc[i][3] + bv.w);
        if (add) {
            float4 ad = *(const float4*)(add + (size_t)m * Nt + n0);
            v.x += ad.x; v.y += ad.y; v.z += ad.z; v.w += ad.w;
        }
        if (RELU_STORE) {
            v.x = fmaxf(v.x, 0.f); v.y = fmaxf(v.y, 0.f);
            v.z = fmaxf(v.z, 0.f); v.w = fmaxf(v.w, 0.f);
        }
        *(float4*)(C + (size_t)m * Nt + n0) = v;
    }
}

__global__ __launch_bounds__(256, 2) void mega_kernel(KParams p)
{
    cg::grid_group grid = cg::this_grid();

    __shared__ float As[16][68], Ws[16][68];
    __shared__ float simsL[MM];
    __shared__ int   cids[MM];
    __shared__ int   selr[KTOP], sele[KTOP];
    __shared__ float avg[256], partial[512], red[256];
    __shared__ float rs[4], rq[4];
    __shared__ int   nsel;

    const int t    = threadIdx.x;
    const int lane = t & 63, wv = t >> 6;

    // ---------------- Phase 1: cosine sims (barrier-free gather) -----------
    {
        const int gw   = blockIdx.x * 4 + wv;      // global wave id
        const int quad = lane >> 2, ql = lane & 3; // 4 lanes per neighbor row
        for (int task = gw; task < 2058 * 13; task += GRID * 4) {
            int rh = task / 13;
            int slice = task - rh * 13;
            const int* conn; int eid;
            if (rh < BB)            { conn = p.qlc + rh * (MM * 2);               eid = p.query[rh * 2]; }
            else if (rh < 2 * BB)   { int b = rh - BB;       conn = p.qrc + b * (MM * 2); eid = p.query[b * 2 + 1]; }
            else if (rh < 2 * BB + FEW) { int r = rh - 2 * BB;  conn = p.slc + r * (MM * 2); eid = p.support[r * 2]; }
            else                    { int r = rh - 2 * BB - FEW; conn = p.srrc + r * (MM * 2); eid = p.support[r * 2 + 1]; }

            const float4* cb = (const float4*)(p.emb + (size_t)eid * 128);
            float4 cr[8];
            #pragma unroll
            for (int i = 0; i < 8; ++i) cr[i] = cb[i * 4 + ql];
            float csq = 0.f;
            #pragma unroll
            for (int i = 0; i < 8; ++i)
                csq += cr[i].x * cr[i].x + cr[i].y * cr[i].y + cr[i].z * cr[i].z + cr[i].w * cr[i].w;
            csq += __shfl_xor(csq, 1, 4); csq += __shfl_xor(csq, 2, 4);
            float cn = sqrtf(csq);

            int  j = slice * 16 + quad;
            bool v = j < MM;
            int  rid = v ? conn[j * 2 + 1] : 0;
            const float4* eb = (const float4*)(p.emb + (size_t)rid * 128);
            float num = 0.f, sq = 0.f;
            #pragma unroll
            for (int i = 0; i < 8; ++i) {
                float4 e = eb[i * 4 + ql];
                num += cr[i].x * e.x + cr[i].y * e.y + cr[i].z * e.z + cr[i].w * e.w;
                sq  += e.x * e.x + e.y * e.y + e.z * e.z + e.w * e.w;
            }
            num += __shfl_xor(num, 1, 4); num += __shfl_xor(num, 2, 4);
            sq  += __shfl_xor(sq , 1, 4); sq  += __shfl_xor(sq , 2, 4);
            if (ql == 0 && v) p.sims[rh * MM + j] = num / fmaxf(cn * sqrtf(sq), 1e-8f);
        }
    }
    grid.sync();

    // ---------------- Phase 2: top-K + mean + GCN matvec -------------------
    for (int pr = blockIdx.x; pr < 2058; pr += GRID) {
        const int* conn; int row_out, half;
        if (pr < BB)            { conn = p.qlc + pr * (MM * 2);                 row_out = pr;        half = 0; }
        else if (pr < 2 * BB)   { int b = pr - BB;       conn = p.qrc + b * (MM * 2); row_out = b;   half = 1; }
        else if (pr < 2 * BB + FEW) { int r = pr - 2 * BB;  conn = p.slc + r * (MM * 2); row_out = BB + r; half = 0; }
        else                    { int r = pr - 2 * BB - FEW; conn = p.srrc + r * (MM * 2); row_out = BB + r; half = 1; }

        if (t < MM) { simsL[t] = p.sims[pr * MM + t]; cids[t] = conn[t * 2 + 1]; }
        if (t == 0) nsel = 0;
        __syncthreads();

        if (t < MM) {
            float st = simsL[t];
            int cnt = 0;
            for (int j = 0; j < MM; ++j) {
                float sj = simsL[j];
                cnt += (sj > st) || (sj == st && j < t);
            }
            if (cnt < KTOP) {
                int q = atomicAdd(&nsel, 1);
                selr[q] = conn[t * 2 + 0];
                sele[q] = cids[t];
            }
        }
        __syncthreads();

        {
            const int slot = t & 127;
            const int hpar = t >> 7;
            const bool isEnt = slot >= 64;
            float2 acc = make_float2(0.f, 0.f);
            for (int s = hpar; s < KTOP; s += 2) {
                int rid = isEnt ? sele[s] : selr[s];
                float2 vv = ((const float2*)(p.emb + (size_t)rid * 128))[slot & 63];
                acc.x += vv.x; acc.y += vv.y;
            }
            ((float2*)partial)[t] = acc;
        }
        __syncthreads();
        if (t < 128) {
            float2 a = ((float2*)partial)[t];
            float2 b = ((float2*)partial)[t + 128];
            ((float2*)avg)[t] = make_float2((a.x + b.x) * (1.0f / KTOP),
                                            (a.y + b.y) * (1.0f / KTOP));
        }
        __syncthreads();
        {
            const int d   = t & 127;
            const int c0i = (t >> 7) * 128;
            float acc = 0.0f;
            const float* wrow = p.gcn_W + d * 256 + c0i;
            #pragma unroll 4
            for (int c = 0; c < 128; ++c) acc += wrow[c] * avg[c0i + c];
            red[t] = acc;
        }
        __syncthreads();
        if (t < 128) {
            float o = red[t] + red[t + 128] + p.gcn_bias[t] + p.gcn_b[t];
            p.qn2[row_out * 256 + half * 128 + t] = tanhf(o);
        }
        __syncthreads();
    }
    grid.sync();

    // ---------------- Phase 3: SE GEMM1: h1 = relu(qn2 @ w1^T + b1) --------
    gemm64<true, false>(p.qn2, p.w1, p.b1, nullptr, nullptr, p.h1q, 1088, 512, 256, As, Ws);
    grid.sync();

    // ---------------- Phase 4: SE GEMM2: yq = h1 @ w2^T + b2 + qn2 ---------
    gemm64<false, false>(p.h1q, p.w2, p.b2, nullptr, p.qn2, p.yq, 1088, 256, 512, As, Ws);
    grid.sync();

    // ---------------- Phase 5: LayerNorm (+ support mean/l2norm) -----------
    for (int row = blockIdx.x; row < 1024; row += GRID) {
        __syncthreads();
        float v = p.yq[row * 256 + t];
        float s = v, q = v * v;
        #pragma unroll
        for (int i = 32; i >= 1; i >>= 1) { s += __shfl_xor(s, i, 64); q += __shfl_xor(q, i, 64); }
        if (lane == 0) { rs[wv] = s; rq[wv] = q; }
        __syncthreads();
        float tot = rs[0] + rs[1] + rs[2] + rs[3];
        float totq = rq[0] + rq[1] + rq[2] + rq[3];
        float mu  = tot * (1.0f / 256.0f);
        float var = fmaxf(totq * (1.0f / 256.0f) - mu * mu, 0.0f);
        p.qg2[row * 256 + t] = p.lng[t] * (v - mu) / sqrtf(var + 1e-5f) + p.lnb[t];
    }
    if (blockIdx.x == 0) {   // support rows: LN + mean + l2norm
        float acc = 0.f;
        for (int r = 0; r < FEW; ++r) {
            __syncthreads();
            float v2 = p.yq[(BB + r) * 256 + t];
            float s2 = v2, q2 = v2 * v2;
            #pragma unroll
            for (int i = 32; i >= 1; i >>= 1) { s2 += __shfl_xor(s2, i, 64); q2 += __shfl_xor(q2, i, 64); }
            if (lane == 0) { rs[wv] = s2; rq[wv] = q2; }
            __syncthreads();
            float t2 = rs[0] + rs[1] + rs[2] + rs[3];
            float tq2 = rq[0] + rq[1] + rq[2] + rq[3];
            float mu2 = t2 * (1.0f / 256.0f);
            float vr2 = fmaxf(tq2 * (1.0f / 256.0f) - mu2 * mu2, 0.0f);
            acc += p.lng[t] * (v2 - mu2) / sqrtf(vr2 + 1e-5f) + p.lnb[t];
        }
        acc *= (1.0f / FEW);
        p.sg0[t] = acc;
        __syncthreads();
        float qq = acc * acc;
        #pragma unroll
        for (int i = 32; i >= 1; i >>= 1) qq += __shfl_xor(qq, i, 64);
        if (lane == 0) rq[wv] = qq;
        __syncthreads();
        float nrm = sqrtf(rq[0] + rq[1] + rq[2] + rq[3]);
        p.sgn[t] = acc / fmaxf(nrm, 1e-12f);
    }
    grid.sync();

    // ---------------- Phase 6: gates = qg2 @ Wih'^T + (b_ih+b_hh) ----------
    gemm64<false, true>(p.qg2, p.Wih, p.bih, p.bhh, nullptr, p.gates, 1024, 1024, 256, As, Ws);
    grid.sync();

    // ---------------- Phase 7: LSTM step 1 ---------------------------------
    for (int row = blockIdx.x; row < 1024; row += GRID) {
        const float* gr = p.gates + row * 1024;
        float iv = gr[t], gv = gr[512 + t], ov = gr[768 + t];
        float cv = sigf(iv) * tanhf(gv);              // c0 = 0
        p.c1[row * 256 + t] = cv;
        float hf = sigf(ov) * tanhf(cv);
        p.hr[row * 512 + t]       = p.qg2[row * 256 + t] + hf;  // h1
        p.hr[row * 512 + 256 + t] = p.sg0[t];                   // r (attn == 1)
    }
    grid.sync();

    // ---------------- Phase 8: gates += hr @ Whh'^T ------------------------
    gemm64<false, true>(p.hr, p.Whh, nullptr, nullptr, p.gates, p.gates, 1024, 1024, 512, As, Ws);
    grid.sync();

    // ---------------- Phase 9: LSTM step 2 + l2norm + dot ------------------
    for (int row = blockIdx.x; row < 1024; row += GRID) {
        __syncthreads();
        const float* gr = p.gates + row * 1024;
        float iv = gr[t], fv = gr[256 + t], gv = gr[512 + t], ov = gr[768 + t];
        float cv = sigf(fv) * p.c1[row * 256 + t] + sigf(iv) * tanhf(gv);
        float h2 = p.qg2[row * 256 + t] + sigf(ov) * tanhf(cv);
        float nn = h2 * h2, dd = h2 * p.sgn[t];
        #pragma unroll
        for (int i = 32; i >= 1; i >>= 1) { nn += __shfl_xor(nn, i, 64); dd += __shfl_xor(dd, i, 64); }
        if (lane == 0) { rs[wv] = nn; rq[wv] = dd; }
        __syncthreads();
        if (t == 0) {
            float n2 = rs[0] + rs[1] + rs[2] + rs[3];
            float dt = rq[0] + rq[1] + rq[2] + rq[3];
            p.out[row] = dt / fmaxf(sqrtf(n2), 1e-12f);
        }
    }
}

// ======================= FALLBACK PATH (round-3 proven) =====================
__global__ __launch_bounds__(256) void neighbor_kernel(
    const int* __restrict__ query, const int* __restrict__ support,
    const int* __restrict__ q_l_conn, const int* __restrict__ q_r_conn,
    const int* __restrict__ s_l_conn, const int* __restrict__ s_r_conn,
    const float* __restrict__ emb,
    const float* __restrict__ gcn_W, const float* __restrict__ gcn_bias,
    const float* __restrict__ gcn_b, float* __restrict__ qn2)
{
    __shared__ float cent[128];
    __shared__ float sims[MM];
    __shared__ int   cids[MM];
    __shared__ int   selr[KTOP];
    __shared__ int   sele[KTOP];
    __shared__ float avg[256];
    __shared__ float partial[512];
    __shared__ float red[256];
    __shared__ int   nsel;

    const int t   = threadIdx.x;
    const int blk = blockIdx.x;

    const int* conn; int eid, row_out, half;
    if (blk < BB)            { conn = q_l_conn + blk * MM * 2;                eid = query[blk * 2 + 0];              row_out = blk;    half = 0; }
    else if (blk < 2 * BB)   { int b = blk - BB;        conn = q_r_conn + b * MM * 2; eid = query[b * 2 + 1];       row_out = b;      half = 1; }
    else if (blk < 2 * BB + FEW) { int r = blk - 2 * BB;   conn = s_l_conn + r * MM * 2; eid = support[r * 2 + 0];  row_out = BB + r; half = 0; }
    else                     { int r = blk - 2 * BB - FEW; conn = s_r_conn + r * MM * 2; eid = support[r * 2 + 1];  row_out = BB + r; half = 1; }

    if (t < 32)  ((float4*)cent)[t] = ((const float4*)(emb + (size_t)eid * 128))[t];
    if (t < MM)  cids[t] = conn[t * 2 + 1];
    if (t == 0)  nsel = 0;
    __syncthreads();

    const int l4 = t & 3, g = t >> 2;
    float4 cr[8];
    #pragma unroll
    for (int i = 0; i < 8; ++i) cr[i] = ((const float4*)cent)[i * 4 + l4];
    float csq = 0.f;
    #pragma unroll
    for (int i = 0; i < 8; ++i)
        csq += cr[i].x * cr[i].x + cr[i].y * cr[i].y + cr[i].z * cr[i].z + cr[i].w * cr[i].w;
    csq += __shfl_xor(csq, 1, 4);
    csq += __shfl_xor(csq, 2, 4);
    const float cn = sqrtf(csq);

    #pragma unroll
    for (int r = 0; r < 4; ++r) {
        int j = g + (r << 6);
        if (j < MM) {
            const float4* er = (const float4*)(emb + (size_t)cids[j] * 128) + l4;
            float num = 0.f, sq = 0.f;
            #pragma unroll
            for (int i = 0; i < 8; ++i) {
                float4 e = er[i * 4];
                num += cr[i].x * e.x + cr[i].y * e.y + cr[i].z * e.z + cr[i].w * e.w;
                sq  += e.x * e.x + e.y * e.y + e.z * e.z + e.w * e.w;
            }
            num += __shfl_xor(num, 1, 4); num += __shfl_xor(num, 2, 4);
            sq  += __shfl_xor(sq , 1, 4); sq  += __shfl_xor(sq , 2, 4);
            if (l4 == 0) sims[j] = num / fmaxf(cn * sqrtf(sq), 1e-8f);
        }
    }
    __syncthreads();

    if (t < MM) {
        float st = sims[t];
        int cnt = 0;
        for (int j = 0; j < MM; ++j) {
            float sj = sims[j];
            cnt += (sj > st) || (sj == st && j < t);
        }
        if (cnt < KTOP) {
            int p = atomicAdd(&nsel, 1);
            selr[p] = conn[t * 2 + 0];
            sele[p] = cids[t];
        }
    }
    __syncthreads();

    {
        const int slot = t & 127;
        const int hpar = t >> 7;
        const bool isEnt = slot >= 64;
        float2 acc = make_float2(0.f, 0.f);
        for (int s = hpar; s < KTOP; s += 2) {
            int rid = isEnt ? sele[s] : selr[s];
            float2 v = ((const float2*)(emb + (size_t)rid * 128))[slot & 63];
            acc.x += v.x; acc.y += v.y;
        }
        ((float2*)partial)[t] = acc;
    }
    __syncthreads();
    if (t < 128) {
        float2 a = ((float2*)partial)[t];
        float2 b = ((float2*)partial)[t + 128];
        ((float2*)avg)[t] = make_float2((a.x + b.x) * (1.0f / KTOP),
                                        (a.y + b.y) * (1.0f / KTOP));
    }
    __syncthreads();

    {
        const int d   = t & 127;
        const int c0i = (t >> 7) * 128;
        float acc = 0.0f;
        const float* wrow = gcn_W + d * 256 + c0i;
        #pragma unroll 4
        for (int c = 0; c < 128; ++c) acc += wrow[c] * avg[c0i + c];
        red[t] = acc;
    }
    __syncthreads();
    if (t < 128) {
        float o = red[t] + red[t + 128] + gcn_bias[t] + gcn_b[t];
        qn2[row_out * 256 + half * 128 + t] = tanhf(o);
    }
}

template <bool RELU, bool HAS_ADD, bool GMAP>
__global__ __launch_bounds__(256) void gemm_nt(
    const float* __restrict__ A, const float* __restrict__ W,
    const float* __restrict__ bias, const float* __restrict__ add,
    float* __restrict__ C, int M_, int N_, int K_)
{
    __shared__ float As[16][68];
    __shared__ float Ws[16][68];
    const int t  = threadIdx.x;
    const int bm = blockIdx.y * 64, bn = blockIdx.x * 64;
    const int tx = t & 15, ty = t >> 4;
    const int lrow = t >> 2, lk4 = (t & 3) * 4;

    int wrow = bn + lrow;
    if (GMAP) wrow = ((wrow >> 8) << 9) | (wrow & 255);
    const float* Ap = A + (size_t)(bm + lrow) * K_ + lk4;
    const float* Wp = W + (size_t)wrow * K_ + lk4;

    float acc[4][4] = {};
    for (int k0 = 0; k0 < K_; k0 += 16) {
        float4 av = *(const float4*)(Ap + k0);
        float4 wv = *(const float4*)(Wp + k0);
        __syncthreads();
        As[lk4 + 0][lrow] = av.x; As[lk4 + 1][lrow] = av.y;
        As[lk4 + 2][lrow] = av.z; As[lk4 + 3][lrow] = av.w;
        Ws[lk4 + 0][lrow] = wv.x; Ws[lk4 + 1][lrow] = wv.y;
        Ws[lk4 + 2][lrow] = wv.z; Ws[lk4 + 3][lrow] = wv.w;
        __syncthreads();
        #pragma unroll
        for (int kk = 0; kk < 16; ++kk) {
            float4 a = *(const float4*)&As[kk][ty * 4];
            float4 b = *(const float4*)&Ws[kk][tx * 4];
            acc[0][0] += a.x * b.x; acc[0][1] += a.x * b.y; acc[0][2] += a.x * b.z; acc[0][3] += a.x * b.w;
            acc[1][0] += a.y * b.x; acc[1][1] += a.y * b.y; acc[1][2] += a.y * b.z; acc[1][3] += a.y * b.w;
            acc[2][0] += a.z * b.x; acc[2][1] += a.z * b.y; acc[2][2] += a.z * b.z; acc[2][3] += a.z * b.w;
            acc[3][0] += a.w * b.x; acc[3][1] += a.w * b.y; acc[3][2] += a.w * b.z; acc[3][3] += a.w * b.w;
        }
    }

    const int n0 = bn + tx * 4;
    float4 bv = make_float4(0.f, 0.f, 0.f, 0.f);
    if (bias) {
        int nb = GMAP ? (((n0 >> 8) << 9) | (n0 & 255)) : n0;
        bv = *(const float4*)(bias + nb);
    }
    #pragma unroll
    for (int i = 0; i < 4; ++i) {
        int m = bm + ty * 4 + i;
        float4 v = make_float4(acc[i][0] + bv.x, acc[i][1] + bv.y,
                               acc[i][2] + bv.z, acc[i][3] + bv.w);
        if (HAS_ADD) {
            float4 ad = *(const float4*)(add + (size_t)m * N_ + n0);
            v.x += ad.x; v.y += ad.y; v.z += ad.z; v.w += ad.w;
        }
        if (RELU) {
            v.x = fmaxf(v.x, 0.f); v.y = fmaxf(v.y, 0.f);
            v.z = fmaxf(v.z, 0.f); v.w = fmaxf(v.w, 0.f);
        }
        *(float4*)(C + (size_t)m * N_ + n0) = v;
    }
}

__global__ __launch_bounds__(256) void ln_kernel(
    const float* __restrict__ y, const float* __restrict__ g,
    const float* __restrict__ beta, float* __restrict__ out)
{
    __shared__ float rs[4], rq[4];
    const int row = blockIdx.x, t = threadIdx.x;
    const int lane = t & 63, wave = t >> 6;
    float v = y[row * 256 + t];
    float s = v, q = v * v;
    #pragma unroll
    for (int i = 32; i >= 1; i >>= 1) { s += __shfl_xor(s, i, 64); q += __shfl_xor(q, i, 64); }
    if (lane == 0) { rs[wave] = s; rq[wave] = q; }
    __syncthreads();
    float tot  = rs[0] + rs[1] + rs[2] + rs[3];
    float totq = rq[0] + rq[1] + rq[2] + rq[3];
    float mu  = tot * (1.0f / 256.0f);
    float var = fmaxf(totq * (1.0f / 256.0f) - mu * mu, 0.0f);
    out[row * 256 + t] = g[t] * (v - mu) / sqrtf(var + 1e-5f) + beta[t];
}

__global__ __launch_bounds__(256) void support_mean_kernel(
    const float* __restrict__ qg2, float* __restrict__ sg0, float* __restrict__ sgn)
{
    __shared__ float rq[4];
    const int t = threadIdx.x;
    const int lane = t & 63, wave = t >> 6;
    float s = 0.0f;
    #pragma unroll
    for (int r = 0; r < FEW; ++r) s += qg2[(BB + r) * 256 + t];
    s *= (1.0f / FEW);
    sg0[t] = s;
    float q = s * s;
    #pragma unroll
    for (int i = 32; i >= 1; i >>= 1) q += __shfl_xor(q, i, 64);
    if (lane == 0) rq[wave] = q;
    __syncthreads();
    float nrm = sqrtf(rq[0] + rq[1] + rq[2] + rq[3]);
    sgn[t] = s / fmaxf(nrm, 1e-12f);
}

__global__ __launch_bounds__(256) void bsum_kernel(
    const float* __restrict__ a, const float* __restrict__ b, float* __restrict__ o)
{
    int i = blockIdx.x * 256 + threadIdx.x;
    o[i] = a[i] + b[i];
}

__global__ __launch_bounds__(256) void lstm_step1_kernel(
    const float* __restrict__ gates, const float* __restrict__ qg,
    const float* __restrict__ sg0, float* __restrict__ c1, float* __restrict__ hr)
{
    const int row = blockIdx.x, t = threadIdx.x;
    const float* gr = gates + row * 1024;
    float iv = gr[t], gv = gr[512 + t], ov = gr[768 + t];
    float cv = sigf(iv) * tanhf(gv);
    c1[row * 256 + t] = cv;
    float hf = sigf(ov) * tanhf(cv);
    hr[row * 512 + t]       = qg[row * 256 + t] + hf;
    hr[row * 512 + 256 + t] = sg0[t];
}

__global__ __launch_bounds__(256) void lstm_step2_kernel(
    const float* __restrict__ gates, const float* __restrict__ c1,
    const float* __restrict__ qg, const float* __restrict__ sgn,
    float* __restrict__ outv)
{
    __shared__ float rn[4], rd[4];
    const int row = blockIdx.x, t = threadIdx.x;
    const int lane = t & 63, wave = t >> 6;
    const float* gr = gates + row * 1024;
    float iv = gr[t], fv = gr[256 + t], gv = gr[512 + t], ov = gr[768 + t];
    float cv = sigf(fv) * c1[row * 256 + t] + sigf(iv) * tanhf(gv);
    float h2 = qg[row * 256 + t] + sigf(ov) * tanhf(cv);
    float nn = h2 * h2, dd = h2 * sgn[t];
    #pragma unroll
    for (int i = 32; i >= 1; i >>= 1) { nn += __shfl_xor(nn, i, 64); dd += __shfl_xor(dd, i, 64); }
    if (lane == 0) { rn[wave] = nn; rd[wave] = dd; }
    __syncthreads();
    if (t == 0) {
        float n2 = rn[0] + rn[1] + rn[2] + rn[3];
        float dt = rd[0] + rd[1] + rd[2] + rd[3];
        outv[row] = dt / fmaxf(sqrtf(n2), 1e-12f);
    }
}

extern "C" void kernel_launch(void* const* d_in, const int* in_sizes, int n_in,
                              void* d_out, int out_size, void* d_ws, size_t ws_size,
                              hipStream_t stream)
{
    KParams p;
    p.query    = (const int*)d_in[0];
    p.support  = (const int*)d_in[1];
    p.qlc      = (const int*)d_in[2];
    p.qrc      = (const int*)d_in[4];
    p.slc      = (const int*)d_in[6];
    p.srrc     = (const int*)d_in[8];
    p.emb      = (const float*)d_in[10];
    p.gcn_W    = (const float*)d_in[11];
    p.gcn_bias = (const float*)d_in[12];
    p.gcn_b    = (const float*)d_in[13];
    p.w1       = (const float*)d_in[14];
    p.b1       = (const float*)d_in[15];
    p.w2       = (const float*)d_in[16];
    p.b2       = (const float*)d_in[17];
    p.lng      = (const float*)d_in[18];
    p.lnb      = (const float*)d_in[19];
    p.Wih      = (const float*)d_in[20];
    p.Whh      = (const float*)d_in[21];
    p.bih      = (const float*)d_in[22];
    p.bhh      = (const float*)d_in[23];
    p.out      = (float*)d_out;

    float* ws = (float*)d_ws;
    p.qn2   = ws;                        // 1088*256
    p.h1q   = p.qn2   + 1088 * 256;      // 1088*512
    p.yq    = p.h1q   + 1088 * 512;      // 1088*256
    p.qg2   = p.yq    + 1088 * 256;      // 1088*256
    p.sg0   = p.qg2   + 1088 * 256;      // 256
    p.sgn   = p.sg0   + 256;             // 256
    float* bsum = p.sgn + 256;           // 2048 (fallback only)
    p.gates = bsum    + 2048;            // 1024*1024
    p.c1    = p.gates + 1024 * 1024;     // 1024*256
    p.hr    = p.c1    + 1024 * 256;      // 1024*512
    p.sims  = p.gates;                   // overlay: sims dies before gates written

    void* kargs[] = { (void*)&p };
    hipError_t err = hipLaunchCooperativeKernel((void*)mega_kernel, dim3(GRID),
                                                dim3(256), kargs, 0, stream);
    if (err == hipSuccess) return;
    (void)hipGetLastError();   // clear sticky error, take fallback path

    // -------- fallback: proven multi-dispatch pipeline --------
    neighbor_kernel<<<2 * BB + 2 * FEW, 256, 0, stream>>>(
        p.query, p.support, p.qlc, p.qrc, p.slc, p.srrc,
        p.emb, p.gcn_W, p.gcn_bias, p.gcn_b, p.qn2);
    bsum_kernel<<<8, 256, 0, stream>>>(p.bih, p.bhh, bsum);
    gemm_nt<true, false, false><<<dim3(8, 17), 256, 0, stream>>>(
        p.qn2, p.w1, p.b1, nullptr, p.h1q, 1088, 512, 256);
    gemm_nt<false, true, false><<<dim3(4, 17), 256, 0, stream>>>(
        p.h1q, p.w2, p.b2, p.qn2, p.yq, 1088, 256, 512);
    ln_kernel<<<1029, 256, 0, stream>>>(p.yq, p.lng, p.lnb, p.qg2);
    support_mean_kernel<<<1, 256, 0, stream>>>(p.qg2, p.sg0, p.sgn);
    gemm_nt<false, false, true><<<dim3(16, 16), 256, 0, stream>>>(
        p.qg2, p.Wih, bsum, nullptr, p.gates, 1024, 1024, 256);
    lstm_step1_kernel<<<1024, 256, 0, stream>>>(p.gates, p.qg2, p.sg0, p.c1, p.hr);
    gemm_nt<false, true, true><<<dim3(16, 16), 256, 0, stream>>>(
        p.hr, p.Whh, nullptr, p.gates, p.gates, 1024, 1024, 512);
    lstm_step2_kernel<<<1024, 256, 0, stream>>>(p.gates, p.c1, p.qg2, p.sgn, p.out);
}

// Round 7
// 402.282 us; speedup vs baseline: 2.2648x; 2.2648x over previous
//
#include <hip/hip_runtime.h>
#include <math.h>

#define NEMB 200000
#define MM   200
#define KTOP 32
#define BB   1024
#define FEW  5
#define NROW 2058           // 2*BB + 2*FEW (row,half) tasks
#define NSLC 13             // ceil(200/16) 16-row slices

__device__ __forceinline__ float sigf(float x) { return 1.0f / (1.0f + expf(-x)); }

// ---------------------------------------------------------------------------
// K1: sims — barrier-free, one wave per (row, slice-of-16-neighbors).
// 4 lanes per neighbor row: 16 distinct 64B-line groups per load instr,
// 8 independent float4 loads per dot, no LDS, no __syncthreads.
// ---------------------------------------------------------------------------
__global__ __launch_bounds__(256) void sims_kernel(
    const int* __restrict__ query, const int* __restrict__ support,
    const int* __restrict__ qlc, const int* __restrict__ qrc,
    const int* __restrict__ slc, const int* __restrict__ srrc,
    const float* __restrict__ emb, float* __restrict__ sims)
{
    const int wid  = (blockIdx.x * 256 + threadIdx.x) >> 6;   // global wave id
    const int lane = threadIdx.x & 63;
    const int quad = lane >> 2, ql = lane & 3;
    if (wid >= NROW * NSLC) return;

    const int rh = wid / NSLC, slice = wid - rh * NSLC;
    const int* conn; int eid;
    if (rh < BB)                 { conn = qlc + rh * (MM * 2);                 eid = query[rh * 2]; }
    else if (rh < 2 * BB)        { int b = rh - BB;        conn = qrc + b * (MM * 2);  eid = query[b * 2 + 1]; }
    else if (rh < 2 * BB + FEW)  { int r = rh - 2 * BB;    conn = slc + r * (MM * 2);  eid = support[r * 2]; }
    else                         { int r = rh - 2 * BB - FEW; conn = srrc + r * (MM * 2); eid = support[r * 2 + 1]; }

    const float4* cb = (const float4*)(emb + (size_t)eid * 128);
    float4 cr[8];
    #pragma unroll
    for (int i = 0; i < 8; ++i) cr[i] = cb[i * 4 + ql];
    float csq = 0.f;
    #pragma unroll
    for (int i = 0; i < 8; ++i)
        csq += cr[i].x * cr[i].x + cr[i].y * cr[i].y + cr[i].z * cr[i].z + cr[i].w * cr[i].w;
    csq += __shfl_xor(csq, 1, 4); csq += __shfl_xor(csq, 2, 4);
    const float cn = sqrtf(csq);

    const int  j = slice * 16 + quad;
    const bool v = j < MM;
    const int  rid = v ? conn[j * 2 + 1] : 0;
    const float4* eb = (const float4*)(emb + (size_t)rid * 128);
    float num = 0.f, sq = 0.f;
    #pragma unroll
    for (int i = 0; i < 8; ++i) {
        float4 e = eb[i * 4 + ql];
        num += cr[i].x * e.x + cr[i].y * e.y + cr[i].z * e.z + cr[i].w * e.w;
        sq  += e.x * e.x + e.y * e.y + e.z * e.z + e.w * e.w;
    }
    num += __shfl_xor(num, 1, 4); num += __shfl_xor(num, 2, 4);
    sq  += __shfl_xor(sq , 1, 4); sq  += __shfl_xor(sq , 2, 4);
    if (ql == 0 && v) sims[rh * MM + j] = num / fmaxf(cn * sqrtf(sq), 1e-8f);
}

// ---------------------------------------------------------------------------
// K2: select (top-K rank, tie-break lower index) + mean gather + GCN matvec
// ---------------------------------------------------------------------------
__global__ __launch_bounds__(256) void select_kernel(
    const int* __restrict__ query, const int* __restrict__ support,
    const int* __restrict__ qlc, const int* __restrict__ qrc,
    const int* __restrict__ slc, const int* __restrict__ srrc,
    const float* __restrict__ emb, const float* __restrict__ sims,
    const float* __restrict__ gcn_W, const float* __restrict__ gcn_bias,
    const float* __restrict__ gcn_b, float* __restrict__ qn2)
{
    __shared__ float simsL[MM];
    __shared__ int   cids[MM];
    __shared__ int   selr[KTOP], sele[KTOP];
    __shared__ float avg[256], partial[512], red[256];
    __shared__ int   nsel;

    const int t   = threadIdx.x;
    const int blk = blockIdx.x;

    const int* conn; int row_out, half;
    if (blk < BB)                { conn = qlc + blk * (MM * 2);                 row_out = blk;    half = 0; }
    else if (blk < 2 * BB)       { int b = blk - BB;        conn = qrc + b * (MM * 2);  row_out = b;      half = 1; }
    else if (blk < 2 * BB + FEW) { int r = blk - 2 * BB;    conn = slc + r * (MM * 2);  row_out = BB + r; half = 0; }
    else                         { int r = blk - 2 * BB - FEW; conn = srrc + r * (MM * 2); row_out = BB + r; half = 1; }

    if (t < MM) { simsL[t] = sims[blk * MM + t]; cids[t] = conn[t * 2 + 1]; }
    if (t == 0) nsel = 0;
    __syncthreads();

    if (t < MM) {
        float st = simsL[t];
        int cnt = 0;
        for (int j = 0; j < MM; ++j) {
            float sj = simsL[j];
            cnt += (sj > st) || (sj == st && j < t);
        }
        if (cnt < KTOP) {
            int p = atomicAdd(&nsel, 1);
            selr[p] = conn[t * 2 + 0];
            sele[p] = cids[t];
        }
    }
    __syncthreads();

    {
        const int slot = t & 127;
        const int hpar = t >> 7;
        const bool isEnt = slot >= 64;
        float2 acc = make_float2(0.f, 0.f);
        for (int s = hpar; s < KTOP; s += 2) {
            int rid = isEnt ? sele[s] : selr[s];
            float2 v = ((const float2*)(emb + (size_t)rid * 128))[slot & 63];
            acc.x += v.x; acc.y += v.y;
        }
        ((float2*)partial)[t] = acc;
    }
    __syncthreads();
    if (t < 128) {
        float2 a = ((float2*)partial)[t];
        float2 b = ((float2*)partial)[t + 128];
        ((float2*)avg)[t] = make_float2((a.x + b.x) * (1.0f / KTOP),
                                        (a.y + b.y) * (1.0f / KTOP));
    }
    __syncthreads();

    {
        const int d   = t & 127;
        const int c0i = (t >> 7) * 128;
        float acc = 0.0f;
        const float* wrow = gcn_W + d * 256 + c0i;
        #pragma unroll 4
        for (int c = 0; c < 128; ++c) acc += wrow[c] * avg[c0i + c];
        red[t] = acc;
    }
    __syncthreads();
    if (t < 128) {
        float o = red[t] + red[t + 128] + gcn_bias[t] + gcn_b[t];
        qn2[row_out * 256 + half * 128 + t] = tanhf(o);
    }
}

// ---------------------------------------------------------------------------
// Generic fp32 GEMM: C[M,N] = A[M,K] @ W[N',K]^T (+bias+bias2)(+add)(relu)
// GMAP remaps output col n -> W row ((n>>8)<<9)|(n&255)  (gate compaction)
// Block tile 64x64, K-tile 16, 256 threads, 4x4 microtile.
// ---------------------------------------------------------------------------
template <bool RELU, bool HAS_ADD, bool GMAP>
__global__ __launch_bounds__(256) void gemm_nt(
    const float* __restrict__ A, const float* __restrict__ W,
    const float* __restrict__ bias, const float* __restrict__ bias2,
    const float* __restrict__ add, float* __restrict__ C,
    int M_, int N_, int K_)
{
    __shared__ float As[16][68];
    __shared__ float Ws[16][68];
    const int t  = threadIdx.x;
    const int bm = blockIdx.y * 64, bn = blockIdx.x * 64;
    const int tx = t & 15, ty = t >> 4;
    const int lrow = t >> 2, lk4 = (t & 3) * 4;

    int wrow = bn + lrow;
    if (GMAP) wrow = ((wrow >> 8) << 9) | (wrow & 255);
    const float* Ap = A + (size_t)(bm + lrow) * K_ + lk4;
    const float* Wp = W + (size_t)wrow * K_ + lk4;

    float acc[4][4] = {};
    for (int k0 = 0; k0 < K_; k0 += 16) {
        float4 av = *(const float4*)(Ap + k0);
        float4 wv = *(const float4*)(Wp + k0);
        __syncthreads();
        As[lk4 + 0][lrow] = av.x; As[lk4 + 1][lrow] = av.y;
        As[lk4 + 2][lrow] = av.z; As[lk4 + 3][lrow] = av.w;
        Ws[lk4 + 0][lrow] = wv.x; Ws[lk4 + 1][lrow] = wv.y;
        Ws[lk4 + 2][lrow] = wv.z; Ws[lk4 + 3][lrow] = wv.w;
        __syncthreads();
        #pragma unroll
        for (int kk = 0; kk < 16; ++kk) {
            float4 a = *(const float4*)&As[kk][ty * 4];
            float4 b = *(const float4*)&Ws[kk][tx * 4];
            acc[0][0] += a.x * b.x; acc[0][1] += a.x * b.y; acc[0][2] += a.x * b.z; acc[0][3] += a.x * b.w;
            acc[1][0] += a.y * b.x; acc[1][1] += a.y * b.y; acc[1][2] += a.y * b.z; acc[1][3] += a.y * b.w;
            acc[2][0] += a.z * b.x; acc[2][1] += a.z * b.y; acc[2][2] += a.z * b.z; acc[2][3] += a.z * b.w;
            acc[3][0] += a.w * b.x; acc[3][1] += a.w * b.y; acc[3][2] += a.w * b.z; acc[3][3] += a.w * b.w;
        }
    }

    const int n0 = bn + tx * 4;
    float4 bv = make_float4(0.f, 0.f, 0.f, 0.f);
    if (bias) {
        int nb = GMAP ? (((n0 >> 8) << 9) | (n0 & 255)) : n0;
        bv = *(const float4*)(bias + nb);
        if (bias2) {
            float4 b2 = *(const float4*)(bias2 + nb);
            bv.x += b2.x; bv.y += b2.y; bv.z += b2.z; bv.w += b2.w;
        }
    }
    #pragma unroll
    for (int i = 0; i < 4; ++i) {
        int m = bm + ty * 4 + i;
        float4 v = make_float4(acc[i][0] + bv.x, acc[i][1] + bv.y,
                               acc[i][2] + bv.z, acc[i][3] + bv.w);
        if (HAS_ADD) {
            float4 ad = *(const float4*)(add + (size_t)m * N_ + n0);
            v.x += ad.x; v.y += ad.y; v.z += ad.z; v.w += ad.w;
        }
        if (RELU) {
            v.x = fmaxf(v.x, 0.f); v.y = fmaxf(v.y, 0.f);
            v.z = fmaxf(v.z, 0.f); v.w = fmaxf(v.w, 0.f);
        }
        *(float4*)(C + (size_t)m * N_ + n0) = v;
    }
}

// ---------------------------------------------------------------------------
// LayerNorm per row (256 dims); block 1024 also does the 5 support rows +
// mean + l2norm (folds support_mean_kernel away)
// ---------------------------------------------------------------------------
__global__ __launch_bounds__(256) void ln_kernel(
    const float* __restrict__ y, const float* __restrict__ g,
    const float* __restrict__ beta, float* __restrict__ out,
    float* __restrict__ sg0, float* __restrict__ sgn)
{
    __shared__ float rs[4], rq[4];
    const int t = threadIdx.x;
    const int lane = t & 63, wave = t >> 6;

    if (blockIdx.x < 1024) {
        const int row = blockIdx.x;
        float v = y[row * 256 + t];
        float s = v, q = v * v;
        #pragma unroll
        for (int i = 32; i >= 1; i >>= 1) { s += __shfl_xor(s, i, 64); q += __shfl_xor(q, i, 64); }
        if (lane == 0) { rs[wave] = s; rq[wave] = q; }
        __syncthreads();
        float tot  = rs[0] + rs[1] + rs[2] + rs[3];
        float totq = rq[0] + rq[1] + rq[2] + rq[3];
        float mu  = tot * (1.0f / 256.0f);
        float var = fmaxf(totq * (1.0f / 256.0f) - mu * mu, 0.0f);
        out[row * 256 + t] = g[t] * (v - mu) / sqrtf(var + 1e-5f) + beta[t];
    } else {
        // support rows: LN each, mean over FEW, then l2norm
        float acc = 0.f;
        for (int r = 0; r < FEW; ++r) {
            __syncthreads();
            float v = y[(BB + r) * 256 + t];
            float s = v, q = v * v;
            #pragma unroll
            for (int i = 32; i >= 1; i >>= 1) { s += __shfl_xor(s, i, 64); q += __shfl_xor(q, i, 64); }
            if (lane == 0) { rs[wave] = s; rq[wave] = q; }
            __syncthreads();
            float tot  = rs[0] + rs[1] + rs[2] + rs[3];
            float totq = rq[0] + rq[1] + rq[2] + rq[3];
            float mu  = tot * (1.0f / 256.0f);
            float var = fmaxf(totq * (1.0f / 256.0f) - mu * mu, 0.0f);
            acc += g[t] * (v - mu) / sqrtf(var + 1e-5f) + beta[t];
        }
        acc *= (1.0f / FEW);
        sg0[t] = acc;
        __syncthreads();
        float q = acc * acc;
        #pragma unroll
        for (int i = 32; i >= 1; i >>= 1) q += __shfl_xor(q, i, 64);
        if (lane == 0) rq[wave] = q;
        __syncthreads();
        float nrm = sqrtf(rq[0] + rq[1] + rq[2] + rq[3]);
        sgn[t] = acc / fmaxf(nrm, 1e-12f);
    }
}

// gates compact layout: [0:256)=i [256:512)=f [512:768)=g [768:1024)=o
__global__ __launch_bounds__(256) void lstm_step1_kernel(
    const float* __restrict__ gates, const float* __restrict__ qg,
    const float* __restrict__ sg0, float* __restrict__ c1, float* __restrict__ hr)
{
    const int row = blockIdx.x, t = threadIdx.x;
    const float* gr = gates + row * 1024;
    float iv = gr[t], gv = gr[512 + t], ov = gr[768 + t];
    float cv = sigf(iv) * tanhf(gv);          // c0 = 0 => f-term drops
    c1[row * 256 + t] = cv;
    float hf = sigf(ov) * tanhf(cv);
    hr[row * 512 + t]       = qg[row * 256 + t] + hf;  // h1
    hr[row * 512 + 256 + t] = sg0[t];                  // r (softmax over 1 => attn==1)
}

__global__ __launch_bounds__(256) void lstm_step2_kernel(
    const float* __restrict__ gates, const float* __restrict__ c1,
    const float* __restrict__ qg, const float* __restrict__ sgn,
    float* __restrict__ outv)
{
    __shared__ float rn[4], rd[4];
    const int row = blockIdx.x, t = threadIdx.x;
    const int lane = t & 63, wave = t >> 6;
    const float* gr = gates + row * 1024;
    float iv = gr[t], fv = gr[256 + t], gv = gr[512 + t], ov = gr[768 + t];
    float cv = sigf(fv) * c1[row * 256 + t] + sigf(iv) * tanhf(gv);
    float h2 = qg[row * 256 + t] + sigf(ov) * tanhf(cv);
    float nn = h2 * h2, dd = h2 * sgn[t];
    #pragma unroll
    for (int i = 32; i >= 1; i >>= 1) { nn += __shfl_xor(nn, i, 64); dd += __shfl_xor(dd, i, 64); }
    if (lane == 0) { rn[wave] = nn; rd[wave] = dd; }
    __syncthreads();
    if (t == 0) {
        float n2 = rn[0] + rn[1] + rn[2] + rn[3];
        float dt = rd[0] + rd[1] + rd[2] + rd[3];
        outv[row] = dt / fmaxf(sqrtf(n2), 1e-12f);
    }
}

extern "C" void kernel_launch(void* const* d_in, const int* in_sizes, int n_in,
                              void* d_out, int out_size, void* d_ws, size_t ws_size,
                              hipStream_t stream)
{
    const int*   query    = (const int*)d_in[0];
    const int*   support  = (const int*)d_in[1];
    const int*   q_l_conn = (const int*)d_in[2];
    const int*   q_r_conn = (const int*)d_in[4];
    const int*   s_l_conn = (const int*)d_in[6];
    const int*   s_r_conn = (const int*)d_in[8];
    const float* emb      = (const float*)d_in[10];
    const float* gcn_W    = (const float*)d_in[11];
    const float* gcn_bias = (const float*)d_in[12];
    const float* gcn_b    = (const float*)d_in[13];
    const float* se_w1    = (const float*)d_in[14];
    const float* se_b1    = (const float*)d_in[15];
    const float* se_w2    = (const float*)d_in[16];
    const float* se_b2    = (const float*)d_in[17];
    const float* ln_g     = (const float*)d_in[18];
    const float* ln_b     = (const float*)d_in[19];
    const float* W_ih     = (const float*)d_in[20];
    const float* W_hh     = (const float*)d_in[21];
    const float* b_ih     = (const float*)d_in[22];
    const float* b_hh     = (const float*)d_in[23];
    float* out = (float*)d_out;

    float* ws    = (float*)d_ws;
    float* qn2   = ws;                    // 1088*256
    float* h1q   = qn2   + 1088 * 256;    // 1088*512
    float* yq    = h1q   + 1088 * 512;    // 1088*256
    float* qg2   = yq    + 1088 * 256;    // 1088*256
    float* sg0   = qg2   + 1088 * 256;    // 256
    float* sgn   = sg0   + 256;           // 256
    float* gates = sgn   + 256;           // 1024*1024
    float* c1    = gates + 1024 * 1024;   // 1024*256
    float* hr    = c1    + 1024 * 256;    // 1024*512
    float* sims  = gates;                 // overlay: sims (411.6k f) dies before gates

    // 1. sims (barrier-free max-MLP gather)
    const int nwaves = NROW * NSLC;                       // 26754
    sims_kernel<<<(nwaves + 3) / 4, 256, 0, stream>>>(
        query, support, q_l_conn, q_r_conn, s_l_conn, s_r_conn, emb, sims);

    // 2. top-K + mean + GCN matvec -> qn2
    select_kernel<<<NROW, 256, 0, stream>>>(
        query, support, q_l_conn, q_r_conn, s_l_conn, s_r_conn,
        emb, sims, gcn_W, gcn_bias, gcn_b, qn2);

    // 3. SE GEMM1: h1 = relu(qn2 @ w1^T + b1)
    gemm_nt<true, false, false><<<dim3(8, 17), 256, 0, stream>>>(
        qn2, se_w1, se_b1, nullptr, nullptr, h1q, 1088, 512, 256);

    // 4. SE GEMM2: yq = h1 @ w2^T + b2 + qn2
    gemm_nt<false, true, false><<<dim3(4, 17), 256, 0, stream>>>(
        h1q, se_w2, se_b2, nullptr, qn2, yq, 1088, 256, 512);

    // 5. LayerNorm -> qg2 (+ support mean + l2norm in block 1024)
    ln_kernel<<<1025, 256, 0, stream>>>(yq, ln_g, ln_b, qg2, sg0, sgn);

    // 6. gates = qg2 @ W_ih'^T + b_ih + b_hh   (gate-compacted N=1024)
    gemm_nt<false, false, true><<<dim3(16, 16), 256, 0, stream>>>(
        qg2, W_ih, b_ih, b_hh, nullptr, gates, 1024, 1024, 256);

    // 7. LSTM step 1 (c0=0, h_r0=0 => gates==gates_base)
    lstm_step1_kernel<<<1024, 256, 0, stream>>>(gates, qg2, sg0, c1, hr);

    // 8. gates2 = gates_base + hr @ W_hh'^T   (in-place add)
    gemm_nt<false, true, true><<<dim3(16, 16), 256, 0, stream>>>(
        hr, W_hh, nullptr, nullptr, gates, gates, 1024, 1024, 512);

    // 9. LSTM step 2 + l2norm + dot(support_gn)
    lstm_step2_kernel<<<1024, 256, 0, stream>>>(gates, c1, qg2, sgn, out);
}

// Round 8
// 383.896 us; speedup vs baseline: 2.3733x; 1.0479x over previous
//
#include <hip/hip_runtime.h>
#include <math.h>

#define NEMB 200000
#define MM   200
#define KTOP 32
#define BB   1024
#define FEW  5
#define NROW 2058           // 2*BB + 2*FEW (row,half) tasks
#define NSLC 13             // ceil(200/16) 16-row slices

__device__ __forceinline__ float sigf(float x) { return 1.0f / (1.0f + expf(-x)); }

// ---------------------------------------------------------------------------
// K1: sims — barrier-free, one wave per (row, slice-of-16-neighbors).
// 4 lanes per neighbor row: 16 distinct 64B-line groups per load instr,
// 8 independent float4 loads per dot, no LDS, no __syncthreads.
// ---------------------------------------------------------------------------
__global__ __launch_bounds__(256) void sims_kernel(
    const int* __restrict__ query, const int* __restrict__ support,
    const int* __restrict__ qlc, const int* __restrict__ qrc,
    const int* __restrict__ slc, const int* __restrict__ srrc,
    const float* __restrict__ emb, float* __restrict__ sims)
{
    const int wid  = (blockIdx.x * 256 + threadIdx.x) >> 6;   // global wave id
    const int lane = threadIdx.x & 63;
    const int quad = lane >> 2, ql = lane & 3;
    if (wid >= NROW * NSLC) return;

    const int rh = wid / NSLC, slice = wid - rh * NSLC;
    const int* conn; int eid;
    if (rh < BB)                 { conn = qlc + rh * (MM * 2);                 eid = query[rh * 2]; }
    else if (rh < 2 * BB)        { int b = rh - BB;        conn = qrc + b * (MM * 2);  eid = query[b * 2 + 1]; }
    else if (rh < 2 * BB + FEW)  { int r = rh - 2 * BB;    conn = slc + r * (MM * 2);  eid = support[r * 2]; }
    else                         { int r = rh - 2 * BB - FEW; conn = srrc + r * (MM * 2); eid = support[r * 2 + 1]; }

    const float4* cb = (const float4*)(emb + (size_t)eid * 128);
    float4 cr[8];
    #pragma unroll
    for (int i = 0; i < 8; ++i) cr[i] = cb[i * 4 + ql];
    float csq = 0.f;
    #pragma unroll
    for (int i = 0; i < 8; ++i)
        csq += cr[i].x * cr[i].x + cr[i].y * cr[i].y + cr[i].z * cr[i].z + cr[i].w * cr[i].w;
    csq += __shfl_xor(csq, 1, 4); csq += __shfl_xor(csq, 2, 4);
    const float cn = sqrtf(csq);

    const int  j = slice * 16 + quad;
    const bool v = j < MM;
    const int  rid = v ? conn[j * 2 + 1] : 0;
    const float4* eb = (const float4*)(emb + (size_t)rid * 128);
    float num = 0.f, sq = 0.f;
    #pragma unroll
    for (int i = 0; i < 8; ++i) {
        float4 e = eb[i * 4 + ql];
        num += cr[i].x * e.x + cr[i].y * e.y + cr[i].z * e.z + cr[i].w * e.w;
        sq  += e.x * e.x + e.y * e.y + e.z * e.z + e.w * e.w;
    }
    num += __shfl_xor(num, 1, 4); num += __shfl_xor(num, 2, 4);
    sq  += __shfl_xor(sq , 1, 4); sq  += __shfl_xor(sq , 2, 4);
    if (ql == 0 && v) sims[rh * MM + j] = num / fmaxf(cn * sqrtf(sq), 1e-8f);
}

// ---------------------------------------------------------------------------
// K2: select (top-K rank, tie-break lower index) + mean gather + GCN matvec.
// Matvec is wave-coalesced: for each output dim d, all 64 lanes load the
// 1KB gcn_W row as ONE float4 instr (16 lines) + shuffle reduce —
// vs per-thread row walk (64 lines/instr). 8k -> 2k L1 lines per task.
// ---------------------------------------------------------------------------
__global__ __launch_bounds__(256) void select_kernel(
    const int* __restrict__ query, const int* __restrict__ support,
    const int* __restrict__ qlc, const int* __restrict__ qrc,
    const int* __restrict__ slc, const int* __restrict__ srrc,
    const float* __restrict__ emb, const float* __restrict__ sims,
    const float* __restrict__ gcn_W, const float* __restrict__ gcn_bias,
    const float* __restrict__ gcn_b, float* __restrict__ qn2)
{
    __shared__ float simsL[MM];
    __shared__ int   cids[MM];
    __shared__ int   selr[KTOP], sele[KTOP];
    __shared__ float4 avg4[64];            // avg[256] as float4, 16B-aligned
    __shared__ float partial[512], red[128];
    __shared__ int   nsel;

    const int t    = threadIdx.x;
    const int blk  = blockIdx.x;
    const int lane = t & 63, wv = t >> 6;

    const int* conn; int row_out, half;
    if (blk < BB)                { conn = qlc + blk * (MM * 2);                 row_out = blk;    half = 0; }
    else if (blk < 2 * BB)       { int b = blk - BB;        conn = qrc + b * (MM * 2);  row_out = b;      half = 1; }
    else if (blk < 2 * BB + FEW) { int r = blk - 2 * BB;    conn = slc + r * (MM * 2);  row_out = BB + r; half = 0; }
    else                         { int r = blk - 2 * BB - FEW; conn = srrc + r * (MM * 2); row_out = BB + r; half = 1; }

    if (t < MM) { simsL[t] = sims[blk * MM + t]; cids[t] = conn[t * 2 + 1]; }
    if (t == 0) nsel = 0;
    __syncthreads();

    if (t < MM) {
        float st = simsL[t];
        int cnt = 0;
        #pragma unroll 4
        for (int j = 0; j < MM; ++j) {
            float sj = simsL[j];
            cnt += (sj > st) || (sj == st && j < t);
        }
        if (cnt < KTOP) {
            int p = atomicAdd(&nsel, 1);
            selr[p] = conn[t * 2 + 0];
            sele[p] = cids[t];
        }
    }
    __syncthreads();

    // ---- mean over selected K of [rel; ent], float2 coalesced ----
    {
        const int slot = t & 127;          // float2 slot: <64 rel dims, >=64 ent dims
        const int hpar = t >> 7;           // row-parity split
        const bool isEnt = slot >= 64;
        float2 acc = make_float2(0.f, 0.f);
        for (int s = hpar; s < KTOP; s += 2) {
            int rid = isEnt ? sele[s] : selr[s];
            float2 v = ((const float2*)(emb + (size_t)rid * 128))[slot & 63];
            acc.x += v.x; acc.y += v.y;
        }
        ((float2*)partial)[t] = acc;
    }
    __syncthreads();
    if (t < 128) {
        float2 a = ((float2*)partial)[t];
        float2 b = ((float2*)partial)[t + 128];
        ((float2*)avg4)[t] = make_float2((a.x + b.x) * (1.0f / KTOP),
                                         (a.y + b.y) * (1.0f / KTOP));
    }
    __syncthreads();

    // ---- wave-coalesced matvec: wave wv handles d = wv*32 .. wv*32+31 ----
    {
        const float4 av = avg4[lane];
        #pragma unroll 4
        for (int dd = 0; dd < 32; ++dd) {
            const int d = wv * 32 + dd;
            float4 w = ((const float4*)(gcn_W + (size_t)d * 256))[lane];
            float acc = w.x * av.x + w.y * av.y + w.z * av.z + w.w * av.w;
            #pragma unroll
            for (int i = 32; i >= 1; i >>= 1) acc += __shfl_xor(acc, i, 64);
            if (lane == 0) red[d] = acc;
        }
    }
    __syncthreads();
    if (t < 128) {
        float o = red[t] + gcn_bias[t] + gcn_b[t];
        qn2[row_out * 256 + half * 128 + t] = tanhf(o);
    }
}

// ---------------------------------------------------------------------------
// Generic fp32 GEMM: C[M,N] = A[M,K] @ W[N',K]^T (+bias+bias2)(+add)(relu)
// GMAP remaps output col n -> W row ((n>>8)<<9)|(n&255)  (gate compaction)
// Block tile 64x64, K-tile 16, 256 threads, 4x4 microtile.
// ---------------------------------------------------------------------------
template <bool RELU, bool HAS_ADD, bool GMAP>
__global__ __launch_bounds__(256) void gemm_nt(
    const float* __restrict__ A, const float* __restrict__ W,
    const float* __restrict__ bias, const float* __restrict__ bias2,
    const float* __restrict__ add, float* __restrict__ C,
    int M_, int N_, int K_)
{
    __shared__ float As[16][68];
    __shared__ float Ws[16][68];
    const int t  = threadIdx.x;
    const int bm = blockIdx.y * 64, bn = blockIdx.x * 64;
    const int tx = t & 15, ty = t >> 4;
    const int lrow = t >> 2, lk4 = (t & 3) * 4;

    int wrow = bn + lrow;
    if (GMAP) wrow = ((wrow >> 8) << 9) | (wrow & 255);
    const float* Ap = A + (size_t)(bm + lrow) * K_ + lk4;
    const float* Wp = W + (size_t)wrow * K_ + lk4;

    float acc[4][4] = {};
    for (int k0 = 0; k0 < K_; k0 += 16) {
        float4 av = *(const float4*)(Ap + k0);
        float4 wv = *(const float4*)(Wp + k0);
        __syncthreads();
        As[lk4 + 0][lrow] = av.x; As[lk4 + 1][lrow] = av.y;
        As[lk4 + 2][lrow] = av.z; As[lk4 + 3][lrow] = av.w;
        Ws[lk4 + 0][lrow] = wv.x; Ws[lk4 + 1][lrow] = wv.y;
        Ws[lk4 + 2][lrow] = wv.z; Ws[lk4 + 3][lrow] = wv.w;
        __syncthreads();
        #pragma unroll
        for (int kk = 0; kk < 16; ++kk) {
            float4 a = *(const float4*)&As[kk][ty * 4];
            float4 b = *(const float4*)&Ws[kk][tx * 4];
            acc[0][0] += a.x * b.x; acc[0][1] += a.x * b.y; acc[0][2] += a.x * b.z; acc[0][3] += a.x * b.w;
            acc[1][0] += a.y * b.x; acc[1][1] += a.y * b.y; acc[1][2] += a.y * b.z; acc[1][3] += a.y * b.w;
            acc[2][0] += a.z * b.x; acc[2][1] += a.z * b.y; acc[2][2] += a.z * b.z; acc[2][3] += a.z * b.w;
            acc[3][0] += a.w * b.x; acc[3][1] += a.w * b.y; acc[3][2] += a.w * b.z; acc[3][3] += a.w * b.w;
        }
    }

    const int n0 = bn + tx * 4;
    float4 bv = make_float4(0.f, 0.f, 0.f, 0.f);
    if (bias) {
        int nb = GMAP ? (((n0 >> 8) << 9) | (n0 & 255)) : n0;
        bv = *(const float4*)(bias + nb);
        if (bias2) {
            float4 b2 = *(const float4*)(bias2 + nb);
            bv.x += b2.x; bv.y += b2.y; bv.z += b2.z; bv.w += b2.w;
        }
    }
    #pragma unroll
    for (int i = 0; i < 4; ++i) {
        int m = bm + ty * 4 + i;
        float4 v = make_float4(acc[i][0] + bv.x, acc[i][1] + bv.y,
                               acc[i][2] + bv.z, acc[i][3] + bv.w);
        if (HAS_ADD) {
            float4 ad = *(const float4*)(add + (size_t)m * N_ + n0);
            v.x += ad.x; v.y += ad.y; v.z += ad.z; v.w += ad.w;
        }
        if (RELU) {
            v.x = fmaxf(v.x, 0.f); v.y = fmaxf(v.y, 0.f);
            v.z = fmaxf(v.z, 0.f); v.w = fmaxf(v.w, 0.f);
        }
        *(float4*)(C + (size_t)m * N_ + n0) = v;
    }
}

// ---------------------------------------------------------------------------
// LayerNorm per row (256 dims); block 1024 also does the 5 support rows +
// mean + l2norm (folds support_mean_kernel away)
// ---------------------------------------------------------------------------
__global__ __launch_bounds__(256) void ln_kernel(
    const float* __restrict__ y, const float* __restrict__ g,
    const float* __restrict__ beta, float* __restrict__ out,
    float* __restrict__ sg0, float* __restrict__ sgn)
{
    __shared__ float rs[4], rq[4];
    const int t = threadIdx.x;
    const int lane = t & 63, wave = t >> 6;

    if (blockIdx.x < 1024) {
        const int row = blockIdx.x;
        float v = y[row * 256 + t];
        float s = v, q = v * v;
        #pragma unroll
        for (int i = 32; i >= 1; i >>= 1) { s += __shfl_xor(s, i, 64); q += __shfl_xor(q, i, 64); }
        if (lane == 0) { rs[wave] = s; rq[wave] = q; }
        __syncthreads();
        float tot  = rs[0] + rs[1] + rs[2] + rs[3];
        float totq = rq[0] + rq[1] + rq[2] + rq[3];
        float mu  = tot * (1.0f / 256.0f);
        float var = fmaxf(totq * (1.0f / 256.0f) - mu * mu, 0.0f);
        out[row * 256 + t] = g[t] * (v - mu) / sqrtf(var + 1e-5f) + beta[t];
    } else {
        // support rows: LN each, mean over FEW, then l2norm
        float acc = 0.f;
        for (int r = 0; r < FEW; ++r) {
            __syncthreads();
            float v = y[(BB + r) * 256 + t];
            float s = v, q = v * v;
            #pragma unroll
            for (int i = 32; i >= 1; i >>= 1) { s += __shfl_xor(s, i, 64); q += __shfl_xor(q, i, 64); }
            if (lane == 0) { rs[wave] = s; rq[wave] = q; }
            __syncthreads();
            float tot  = rs[0] + rs[1] + rs[2] + rs[3];
            float totq = rq[0] + rq[1] + rq[2] + rq[3];
            float mu  = tot * (1.0f / 256.0f);
            float var = fmaxf(totq * (1.0f / 256.0f) - mu * mu, 0.0f);
            acc += g[t] * (v - mu) / sqrtf(var + 1e-5f) + beta[t];
        }
        acc *= (1.0f / FEW);
        sg0[t] = acc;
        __syncthreads();
        float q = acc * acc;
        #pragma unroll
        for (int i = 32; i >= 1; i >>= 1) q += __shfl_xor(q, i, 64);
        if (lane == 0) rq[wave] = q;
        __syncthreads();
        float nrm = sqrtf(rq[0] + rq[1] + rq[2] + rq[3]);
        sgn[t] = acc / fmaxf(nrm, 1e-12f);
    }
}

// gates compact layout: [0:256)=i [256:512)=f [512:768)=g [768:1024)=o
__global__ __launch_bounds__(256) void lstm_step1_kernel(
    const float* __restrict__ gates, const float* __restrict__ qg,
    const float* __restrict__ sg0, float* __restrict__ c1, float* __restrict__ hr)
{
    const int row = blockIdx.x, t = threadIdx.x;
    const float* gr = gates + row * 1024;
    float iv = gr[t], gv = gr[512 + t], ov = gr[768 + t];
    float cv = sigf(iv) * tanhf(gv);          // c0 = 0 => f-term drops
    c1[row * 256 + t] = cv;
    float hf = sigf(ov) * tanhf(cv);
    hr[row * 512 + t]       = qg[row * 256 + t] + hf;  // h1
    hr[row * 512 + 256 + t] = sg0[t];                  // r (softmax over 1 => attn==1)
}

__global__ __launch_bounds__(256) void lstm_step2_kernel(
    const float* __restrict__ gates, const float* __restrict__ c1,
    const float* __restrict__ qg, const float* __restrict__ sgn,
    float* __restrict__ outv)
{
    __shared__ float rn[4], rd[4];
    const int row = blockIdx.x, t = threadIdx.x;
    const int lane = t & 63, wave = t >> 6;
    const float* gr = gates + row * 1024;
    float iv = gr[t], fv = gr[256 + t], gv = gr[512 + t], ov = gr[768 + t];
    float cv = sigf(fv) * c1[row * 256 + t] + sigf(iv) * tanhf(gv);
    float h2 = qg[row * 256 + t] + sigf(ov) * tanhf(cv);
    float nn = h2 * h2, dd = h2 * sgn[t];
    #pragma unroll
    for (int i = 32; i >= 1; i >>= 1) { nn += __shfl_xor(nn, i, 64); dd += __shfl_xor(dd, i, 64); }
    if (lane == 0) { rn[wave] = nn; rd[wave] = dd; }
    __syncthreads();
    if (t == 0) {
        float n2 = rn[0] + rn[1] + rn[2] + rn[3];
        float dt = rd[0] + rd[1] + rd[2] + rd[3];
        outv[row] = dt / fmaxf(sqrtf(n2), 1e-12f);
    }
}

extern "C" void kernel_launch(void* const* d_in, const int* in_sizes, int n_in,
                              void* d_out, int out_size, void* d_ws, size_t ws_size,
                              hipStream_t stream)
{
    const int*   query    = (const int*)d_in[0];
    const int*   support  = (const int*)d_in[1];
    const int*   q_l_conn = (const int*)d_in[2];
    const int*   q_r_conn = (const int*)d_in[4];
    const int*   s_l_conn = (const int*)d_in[6];
    const int*   s_r_conn = (const int*)d_in[8];
    const float* emb      = (const float*)d_in[10];
    const float* gcn_W    = (const float*)d_in[11];
    const float* gcn_bias = (const float*)d_in[12];
    const float* gcn_b    = (const float*)d_in[13];
    const float* se_w1    = (const float*)d_in[14];
    const float* se_b1    = (const float*)d_in[15];
    const float* se_w2    = (const float*)d_in[16];
    const float* se_b2    = (const float*)d_in[17];
    const float* ln_g     = (const float*)d_in[18];
    const float* ln_b     = (const float*)d_in[19];
    const float* W_ih     = (const float*)d_in[20];
    const float* W_hh     = (const float*)d_in[21];
    const float* b_ih     = (const float*)d_in[22];
    const float* b_hh     = (const float*)d_in[23];
    float* out = (float*)d_out;

    float* ws    = (float*)d_ws;
    float* qn2   = ws;                    // 1088*256
    float* h1q   = qn2   + 1088 * 256;    // 1088*512
    float* yq    = h1q   + 1088 * 512;    // 1088*256
    float* qg2   = yq    + 1088 * 256;    // 1088*256
    float* sg0   = qg2   + 1088 * 256;    // 256
    float* sgn   = sg0   + 256;           // 256
    float* gates = sgn   + 256;           // 1024*1024
    float* c1    = gates + 1024 * 1024;   // 1024*256
    float* hr    = c1    + 1024 * 256;    // 1024*512
    float* sims  = gates;                 // overlay: sims (411.6k f) dies before gates

    // 1. sims (barrier-free max-MLP gather)
    const int nwaves = NROW * NSLC;                       // 26754
    sims_kernel<<<(nwaves + 3) / 4, 256, 0, stream>>>(
        query, support, q_l_conn, q_r_conn, s_l_conn, s_r_conn, emb, sims);

    // 2. top-K + mean + GCN matvec -> qn2
    select_kernel<<<NROW, 256, 0, stream>>>(
        query, support, q_l_conn, q_r_conn, s_l_conn, s_r_conn,
        emb, sims, gcn_W, gcn_bias, gcn_b, qn2);

    // 3. SE GEMM1: h1 = relu(qn2 @ w1^T + b1)
    gemm_nt<true, false, false><<<dim3(8, 17), 256, 0, stream>>>(
        qn2, se_w1, se_b1, nullptr, nullptr, h1q, 1088, 512, 256);

    // 4. SE GEMM2: yq = h1 @ w2^T + b2 + qn2
    gemm_nt<false, true, false><<<dim3(4, 17), 256, 0, stream>>>(
        h1q, se_w2, se_b2, nullptr, qn2, yq, 1088, 256, 512);

    // 5. LayerNorm -> qg2 (+ support mean + l2norm in block 1024)
    ln_kernel<<<1025, 256, 0, stream>>>(yq, ln_g, ln_b, qg2, sg0, sgn);

    // 6. gates = qg2 @ W_ih'^T + b_ih + b_hh   (gate-compacted N=1024)
    gemm_nt<false, false, true><<<dim3(16, 16), 256, 0, stream>>>(
        qg2, W_ih, b_ih, b_hh, nullptr, gates, 1024, 1024, 256);

    // 7. LSTM step 1 (c0=0, h_r0=0 => gates==gates_base)
    lstm_step1_kernel<<<1024, 256, 0, stream>>>(gates, qg2, sg0, c1, hr);

    // 8. gates2 = gates_base + hr @ W_hh'^T   (in-place add)
    gemm_nt<false, true, true><<<dim3(16, 16), 256, 0, stream>>>(
        hr, W_hh, nullptr, nullptr, gates, gates, 1024, 1024, 512);

    // 9. LSTM step 2 + l2norm + dot(support_gn)
    lstm_step2_kernel<<<1024, 256, 0, stream>>>(gates, c1, qg2, sgn, out);
}

// Round 9
// 359.312 us; speedup vs baseline: 2.5357x; 1.0684x over previous
//
#include <hip/hip_runtime.h>
#include <math.h>

#define NEMB 200000
#define MM   200
#define KTOP 32
#define BB   1024
#define FEW  5
#define NROW 2058           // 2*BB + 2*FEW (row,half) tasks
#define NSLC 13             // ceil(200/16) 16-row slices

__device__ __forceinline__ float sigf(float x) { return 1.0f / (1.0f + expf(-x)); }

// ---------------------------------------------------------------------------
// K1: sims — barrier-free, one wave per (row, slice-of-16-neighbors).
// ---------------------------------------------------------------------------
__global__ __launch_bounds__(256) void sims_kernel(
    const int* __restrict__ query, const int* __restrict__ support,
    const int* __restrict__ qlc, const int* __restrict__ qrc,
    const int* __restrict__ slc, const int* __restrict__ srrc,
    const float* __restrict__ emb, float* __restrict__ sims)
{
    const int wid  = (blockIdx.x * 256 + threadIdx.x) >> 6;   // global wave id
    const int lane = threadIdx.x & 63;
    const int quad = lane >> 2, ql = lane & 3;
    if (wid >= NROW * NSLC) return;

    const int rh = wid / NSLC, slice = wid - rh * NSLC;
    const int* conn; int eid;
    if (rh < BB)                 { conn = qlc + rh * (MM * 2);                 eid = query[rh * 2]; }
    else if (rh < 2 * BB)        { int b = rh - BB;        conn = qrc + b * (MM * 2);  eid = query[b * 2 + 1]; }
    else if (rh < 2 * BB + FEW)  { int r = rh - 2 * BB;    conn = slc + r * (MM * 2);  eid = support[r * 2]; }
    else                         { int r = rh - 2 * BB - FEW; conn = srrc + r * (MM * 2); eid = support[r * 2 + 1]; }

    const float4* cb = (const float4*)(emb + (size_t)eid * 128);
    float4 cr[8];
    #pragma unroll
    for (int i = 0; i < 8; ++i) cr[i] = cb[i * 4 + ql];
    float csq = 0.f;
    #pragma unroll
    for (int i = 0; i < 8; ++i)
        csq += cr[i].x * cr[i].x + cr[i].y * cr[i].y + cr[i].z * cr[i].z + cr[i].w * cr[i].w;
    csq += __shfl_xor(csq, 1, 4); csq += __shfl_xor(csq, 2, 4);
    const float cn = sqrtf(csq);

    const int  j = slice * 16 + quad;
    const bool v = j < MM;
    const int  rid = v ? conn[j * 2 + 1] : 0;
    const float4* eb = (const float4*)(emb + (size_t)rid * 128);
    float num = 0.f, sq = 0.f;
    #pragma unroll
    for (int i = 0; i < 8; ++i) {
        float4 e = eb[i * 4 + ql];
        num += cr[i].x * e.x + cr[i].y * e.y + cr[i].z * e.z + cr[i].w * e.w;
        sq  += e.x * e.x + e.y * e.y + e.z * e.z + e.w * e.w;
    }
    num += __shfl_xor(num, 1, 4); num += __shfl_xor(num, 2, 4);
    sq  += __shfl_xor(sq , 1, 4); sq  += __shfl_xor(sq , 2, 4);
    if (ql == 0 && v) sims[rh * MM + j] = num / fmaxf(cn * sqrtf(sq), 1e-8f);
}

// ---------------------------------------------------------------------------
// K2: rank (top-K, tie-break lower index) + mean gather -> avgbuf[task,256].
// No matvec here — that moved to a GEMM (gcn_gemm_kernel).
// ---------------------------------------------------------------------------
__global__ __launch_bounds__(256) void rank_avg_kernel(
    const int* __restrict__ query, const int* __restrict__ support,
    const int* __restrict__ qlc, const int* __restrict__ qrc,
    const int* __restrict__ slc, const int* __restrict__ srrc,
    const float* __restrict__ emb, const float* __restrict__ sims,
    float* __restrict__ avgbuf)
{
    __shared__ float simsL[MM];
    __shared__ int   cids[MM];
    __shared__ int   selr[KTOP], sele[KTOP];
    __shared__ float partial[512];
    __shared__ int   nsel;

    const int t   = threadIdx.x;
    const int blk = blockIdx.x;

    const int* conn;
    if (blk < BB)                { conn = qlc + blk * (MM * 2); }
    else if (blk < 2 * BB)       { conn = qrc + (blk - BB) * (MM * 2); }
    else if (blk < 2 * BB + FEW) { conn = slc + (blk - 2 * BB) * (MM * 2); }
    else                         { conn = srrc + (blk - 2 * BB - FEW) * (MM * 2); }

    if (t < MM) { simsL[t] = sims[blk * MM + t]; cids[t] = conn[t * 2 + 1]; }
    if (t == 0) nsel = 0;
    __syncthreads();

    if (t < MM) {
        float st = simsL[t];
        int cnt = 0;
        #pragma unroll 4
        for (int j = 0; j < MM; ++j) {
            float sj = simsL[j];
            cnt += (sj > st) || (sj == st && j < t);
        }
        if (cnt < KTOP) {
            int p = atomicAdd(&nsel, 1);
            selr[p] = conn[t * 2 + 0];
            sele[p] = cids[t];
        }
    }
    __syncthreads();

    // mean over selected K of [rel; ent], float2 coalesced
    {
        const int slot = t & 127;          // float2 slot: <64 rel dims, >=64 ent dims
        const int hpar = t >> 7;           // row-parity split
        const bool isEnt = slot >= 64;
        float2 acc = make_float2(0.f, 0.f);
        for (int s = hpar; s < KTOP; s += 2) {
            int rid = isEnt ? sele[s] : selr[s];
            float2 v = ((const float2*)(emb + (size_t)rid * 128))[slot & 63];
            acc.x += v.x; acc.y += v.y;
        }
        ((float2*)partial)[t] = acc;
    }
    __syncthreads();
    if (t < 128) {
        float2 a = ((float2*)partial)[t];
        float2 b = ((float2*)partial)[t + 128];
        ((float2*)(avgbuf + (size_t)blk * 256))[t] =
            make_float2((a.x + b.x) * (1.0f / KTOP), (a.y + b.y) * (1.0f / KTOP));
    }
}

// ---------------------------------------------------------------------------
// K3: GCN matvec as GEMM: qn2' = tanh(avgbuf[2058,256] @ gcn_W[128,256]^T + b)
// 64x64 tiles, interleaved (row_out, half) write. Rows >= NROW guarded.
// ---------------------------------------------------------------------------
__global__ __launch_bounds__(256) void gcn_gemm_kernel(
    const float* __restrict__ A, const float* __restrict__ W,
    const float* __restrict__ gcn_bias, const float* __restrict__ gcn_b,
    float* __restrict__ qn2)
{
    __shared__ float As[16][68];
    __shared__ float Ws[16][68];
    const int t  = threadIdx.x;
    const int bm = blockIdx.y * 64, bn = blockIdx.x * 64;
    const int tx = t & 15, ty = t >> 4;
    const int lrow = t >> 2, lk4 = (t & 3) * 4;

    const float* Ap = A + (size_t)(bm + lrow) * 256 + lk4;
    const float* Wp = W + (size_t)(bn + lrow) * 256 + lk4;

    float acc[4][4] = {};
    for (int k0 = 0; k0 < 256; k0 += 16) {
        float4 av = *(const float4*)(Ap + k0);
        float4 wv = *(const float4*)(Wp + k0);
        __syncthreads();
        As[lk4 + 0][lrow] = av.x; As[lk4 + 1][lrow] = av.y;
        As[lk4 + 2][lrow] = av.z; As[lk4 + 3][lrow] = av.w;
        Ws[lk4 + 0][lrow] = wv.x; Ws[lk4 + 1][lrow] = wv.y;
        Ws[lk4 + 2][lrow] = wv.z; Ws[lk4 + 3][lrow] = wv.w;
        __syncthreads();
        #pragma unroll
        for (int kk = 0; kk < 16; ++kk) {
            float4 a = *(const float4*)&As[kk][ty * 4];
            float4 b = *(const float4*)&Ws[kk][tx * 4];
            acc[0][0] += a.x * b.x; acc[0][1] += a.x * b.y; acc[0][2] += a.x * b.z; acc[0][3] += a.x * b.w;
            acc[1][0] += a.y * b.x; acc[1][1] += a.y * b.y; acc[1][2] += a.y * b.z; acc[1][3] += a.y * b.w;
            acc[2][0] += a.z * b.x; acc[2][1] += a.z * b.y; acc[2][2] += a.z * b.z; acc[2][3] += a.z * b.w;
            acc[3][0] += a.w * b.x; acc[3][1] += a.w * b.y; acc[3][2] += a.w * b.z; acc[3][3] += a.w * b.w;
        }
    }

    const int n0 = bn + tx * 4;
    float4 bv = *(const float4*)(gcn_bias + n0);
    float4 b2 = *(const float4*)(gcn_b + n0);
    bv.x += b2.x; bv.y += b2.y; bv.z += b2.z; bv.w += b2.w;

    #pragma unroll
    for (int i = 0; i < 4; ++i) {
        int tk = bm + ty * 4 + i;
        if (tk >= NROW) continue;
        int row_out, half;
        if (tk < BB)                { row_out = tk;                 half = 0; }
        else if (tk < 2 * BB)       { row_out = tk - BB;            half = 1; }
        else if (tk < 2 * BB + FEW) { row_out = BB + tk - 2 * BB;   half = 0; }
        else                        { row_out = BB + tk - 2 * BB - FEW; half = 1; }
        float4 v = make_float4(tanhf(acc[i][0] + bv.x), tanhf(acc[i][1] + bv.y),
                               tanhf(acc[i][2] + bv.z), tanhf(acc[i][3] + bv.w));
        *(float4*)(qn2 + (size_t)row_out * 256 + half * 128 + n0) = v;
    }
}

// ---------------------------------------------------------------------------
// gemm32: C[M,N] = A[M,K] @ W[N',K]^T (+bias+bias2)(+add)(relu)
// 32x64 tile (2x blocks vs 64x64 -> 2 blocks/CU on 1024-square GEMMs),
// 256 threads, 2x4 microtile. GMAP = LSTM gate compaction.
// ---------------------------------------------------------------------------
template <bool RELU, bool HAS_ADD, bool GMAP>
__global__ __launch_bounds__(256) void gemm32(
    const float* __restrict__ A, const float* __restrict__ W,
    const float* __restrict__ bias, const float* __restrict__ bias2,
    const float* __restrict__ add, float* __restrict__ C,
    int M_, int N_, int K_)
{
    __shared__ float As[16][36];
    __shared__ float Ws[16][68];
    const int t  = threadIdx.x;
    const int bm = blockIdx.y * 32, bn = blockIdx.x * 64;
    const int tx = t & 15, ty = t >> 4;
    const int lrow = t >> 2, lk4 = (t & 3) * 4;

    int wrow = bn + lrow;
    if (GMAP) wrow = ((wrow >> 8) << 9) | (wrow & 255);
    const float* Wp = W + (size_t)wrow * K_ + lk4;
    const float* Ap = A + (size_t)(bm + lrow) * K_ + lk4;   // valid only t<128

    float acc[2][4] = {};
    for (int k0 = 0; k0 < K_; k0 += 16) {
        float4 wv = *(const float4*)(Wp + k0);
        float4 av = make_float4(0.f, 0.f, 0.f, 0.f);
        if (t < 128) av = *(const float4*)(Ap + k0);
        __syncthreads();
        Ws[lk4 + 0][lrow] = wv.x; Ws[lk4 + 1][lrow] = wv.y;
        Ws[lk4 + 2][lrow] = wv.z; Ws[lk4 + 3][lrow] = wv.w;
        if (t < 128) {
            As[lk4 + 0][lrow] = av.x; As[lk4 + 1][lrow] = av.y;
            As[lk4 + 2][lrow] = av.z; As[lk4 + 3][lrow] = av.w;
        }
        __syncthreads();
        #pragma unroll
        for (int kk = 0; kk < 16; ++kk) {
            float2 a = *(const float2*)&As[kk][ty * 2];
            float4 b = *(const float4*)&Ws[kk][tx * 4];
            acc[0][0] += a.x * b.x; acc[0][1] += a.x * b.y; acc[0][2] += a.x * b.z; acc[0][3] += a.x * b.w;
            acc[1][0] += a.y * b.x; acc[1][1] += a.y * b.y; acc[1][2] += a.y * b.z; acc[1][3] += a.y * b.w;
        }
    }

    const int n0 = bn + tx * 4;
    float4 bv = make_float4(0.f, 0.f, 0.f, 0.f);
    if (bias) {
        int nb = GMAP ? (((n0 >> 8) << 9) | (n0 & 255)) : n0;
        bv = *(const float4*)(bias + nb);
        if (bias2) {
            float4 b2 = *(const float4*)(bias2 + nb);
            bv.x += b2.x; bv.y += b2.y; bv.z += b2.z; bv.w += b2.w;
        }
    }
    #pragma unroll
    for (int i = 0; i < 2; ++i) {
        int m = bm + ty * 2 + i;
        float4 v = make_float4(acc[i][0] + bv.x, acc[i][1] + bv.y,
                               acc[i][2] + bv.z, acc[i][3] + bv.w);
        if (HAS_ADD) {
            float4 ad = *(const float4*)(add + (size_t)m * N_ + n0);
            v.x += ad.x; v.y += ad.y; v.z += ad.z; v.w += ad.w;
        }
        if (RELU) {
            v.x = fmaxf(v.x, 0.f); v.y = fmaxf(v.y, 0.f);
            v.z = fmaxf(v.z, 0.f); v.w = fmaxf(v.w, 0.f);
        }
        *(float4*)(C + (size_t)m * N_ + n0) = v;
    }
}

// ---------------------------------------------------------------------------
// LayerNorm per row (256 dims); block 1024 also does the 5 support rows +
// mean + l2norm
// ---------------------------------------------------------------------------
__global__ __launch_bounds__(256) void ln_kernel(
    const float* __restrict__ y, const float* __restrict__ g,
    const float* __restrict__ beta, float* __restrict__ out,
    float* __restrict__ sg0, float* __restrict__ sgn)
{
    __shared__ float rs[4], rq[4];
    const int t = threadIdx.x;
    const int lane = t & 63, wave = t >> 6;

    if (blockIdx.x < 1024) {
        const int row = blockIdx.x;
        float v = y[row * 256 + t];
        float s = v, q = v * v;
        #pragma unroll
        for (int i = 32; i >= 1; i >>= 1) { s += __shfl_xor(s, i, 64); q += __shfl_xor(q, i, 64); }
        if (lane == 0) { rs[wave] = s; rq[wave] = q; }
        __syncthreads();
        float tot  = rs[0] + rs[1] + rs[2] + rs[3];
        float totq = rq[0] + rq[1] + rq[2] + rq[3];
        float mu  = tot * (1.0f / 256.0f);
        float var = fmaxf(totq * (1.0f / 256.0f) - mu * mu, 0.0f);
        out[row * 256 + t] = g[t] * (v - mu) / sqrtf(var + 1e-5f) + beta[t];
    } else {
        float acc = 0.f;
        for (int r = 0; r < FEW; ++r) {
            __syncthreads();
            float v = y[(BB + r) * 256 + t];
            float s = v, q = v * v;
            #pragma unroll
            for (int i = 32; i >= 1; i >>= 1) { s += __shfl_xor(s, i, 64); q += __shfl_xor(q, i, 64); }
            if (lane == 0) { rs[wave] = s; rq[wave] = q; }
            __syncthreads();
            float tot  = rs[0] + rs[1] + rs[2] + rs[3];
            float totq = rq[0] + rq[1] + rq[2] + rq[3];
            float mu  = tot * (1.0f / 256.0f);
            float var = fmaxf(totq * (1.0f / 256.0f) - mu * mu, 0.0f);
            acc += g[t] * (v - mu) / sqrtf(var + 1e-5f) + beta[t];
        }
        acc *= (1.0f / FEW);
        sg0[t] = acc;
        __syncthreads();
        float q = acc * acc;
        #pragma unroll
        for (int i = 32; i >= 1; i >>= 1) q += __shfl_xor(q, i, 64);
        if (lane == 0) rq[wave] = q;
        __syncthreads();
        float nrm = sqrtf(rq[0] + rq[1] + rq[2] + rq[3]);
        sgn[t] = acc / fmaxf(nrm, 1e-12f);
    }
}

// gates compact layout: [0:256)=i [256:512)=f [512:768)=g [768:1024)=o
__global__ __launch_bounds__(256) void lstm_step1_kernel(
    const float* __restrict__ gates, const float* __restrict__ qg,
    const float* __restrict__ sg0, float* __restrict__ c1, float* __restrict__ hr)
{
    const int row = blockIdx.x, t = threadIdx.x;
    const float* gr = gates + row * 1024;
    float iv = gr[t], gv = gr[512 + t], ov = gr[768 + t];
    float cv = sigf(iv) * tanhf(gv);          // c0 = 0 => f-term drops
    c1[row * 256 + t] = cv;
    float hf = sigf(ov) * tanhf(cv);
    hr[row * 512 + t]       = qg[row * 256 + t] + hf;  // h1
    hr[row * 512 + 256 + t] = sg0[t];                  // r (softmax over 1 => attn==1)
}

__global__ __launch_bounds__(256) void lstm_step2_kernel(
    const float* __restrict__ gates, const float* __restrict__ c1,
    const float* __restrict__ qg, const float* __restrict__ sgn,
    float* __restrict__ outv)
{
    __shared__ float rn[4], rd[4];
    const int row = blockIdx.x, t = threadIdx.x;
    const int lane = t & 63, wave = t >> 6;
    const float* gr = gates + row * 1024;
    float iv = gr[t], fv = gr[256 + t], gv = gr[512 + t], ov = gr[768 + t];
    float cv = sigf(fv) * c1[row * 256 + t] + sigf(iv) * tanhf(gv);
    float h2 = qg[row * 256 + t] + sigf(ov) * tanhf(cv);
    float nn = h2 * h2, dd = h2 * sgn[t];
    #pragma unroll
    for (int i = 32; i >= 1; i >>= 1) { nn += __shfl_xor(nn, i, 64); dd += __shfl_xor(dd, i, 64); }
    if (lane == 0) { rn[wave] = nn; rd[wave] = dd; }
    __syncthreads();
    if (t == 0) {
        float n2 = rn[0] + rn[1] + rn[2] + rn[3];
        float dt = rd[0] + rd[1] + rd[2] + rd[3];
        outv[row] = dt / fmaxf(sqrtf(n2), 1e-12f);
    }
}

extern "C" void kernel_launch(void* const* d_in, const int* in_sizes, int n_in,
                              void* d_out, int out_size, void* d_ws, size_t ws_size,
                              hipStream_t stream)
{
    const int*   query    = (const int*)d_in[0];
    const int*   support  = (const int*)d_in[1];
    const int*   q_l_conn = (const int*)d_in[2];
    const int*   q_r_conn = (const int*)d_in[4];
    const int*   s_l_conn = (const int*)d_in[6];
    const int*   s_r_conn = (const int*)d_in[8];
    const float* emb      = (const float*)d_in[10];
    const float* gcn_W    = (const float*)d_in[11];
    const float* gcn_bias = (const float*)d_in[12];
    const float* gcn_b    = (const float*)d_in[13];
    const float* se_w1    = (const float*)d_in[14];
    const float* se_b1    = (const float*)d_in[15];
    const float* se_w2    = (const float*)d_in[16];
    const float* se_b2    = (const float*)d_in[17];
    const float* ln_g     = (const float*)d_in[18];
    const float* ln_b     = (const float*)d_in[19];
    const float* W_ih     = (const float*)d_in[20];
    const float* W_hh     = (const float*)d_in[21];
    const float* b_ih     = (const float*)d_in[22];
    const float* b_hh     = (const float*)d_in[23];
    float* out = (float*)d_out;

    float* ws     = (float*)d_ws;
    float* qn2    = ws;                    // 1088*256
    float* h1q    = qn2    + 1088 * 256;   // 1088*512
    float* yq     = h1q    + 1088 * 512;   // 1088*256
    float* qg2    = yq     + 1088 * 256;   // 1088*256
    float* sg0    = qg2    + 1088 * 256;   // 256
    float* sgn    = sg0    + 256;          // 256
    float* gates  = sgn    + 256;          // 1024*1024
    float* c1     = gates  + 1024 * 1024;  // 1024*256
    float* hr     = c1     + 1024 * 256;   // 1024*512
    float* avgbuf = hr     + 1024 * 512;   // 2112*256 (rows >= NROW read-only pad)
    float* sims   = gates;                 // overlay: sims dies before gates written

    // 1. sims (barrier-free max-MLP gather)
    const int nwaves = NROW * NSLC;                       // 26754
    sims_kernel<<<(nwaves + 3) / 4, 256, 0, stream>>>(
        query, support, q_l_conn, q_r_conn, s_l_conn, s_r_conn, emb, sims);

    // 2. top-K rank + mean gather -> avgbuf
    rank_avg_kernel<<<NROW, 256, 0, stream>>>(
        query, support, q_l_conn, q_r_conn, s_l_conn, s_r_conn,
        emb, sims, avgbuf);

    // 3. GCN matvec as GEMM (tanh + interleave epilogue) -> qn2
    gcn_gemm_kernel<<<dim3(2, 33), 256, 0, stream>>>(
        avgbuf, gcn_W, gcn_bias, gcn_b, qn2);

    // 4. SE GEMM1: h1 = relu(qn2 @ w1^T + b1)
    gemm32<true, false, false><<<dim3(8, 34), 256, 0, stream>>>(
        qn2, se_w1, se_b1, nullptr, nullptr, h1q, 1088, 512, 256);

    // 5. SE GEMM2: yq = h1 @ w2^T + b2 + qn2
    gemm32<false, true, false><<<dim3(4, 34), 256, 0, stream>>>(
        h1q, se_w2, se_b2, nullptr, qn2, yq, 1088, 256, 512);

    // 6. LayerNorm -> qg2 (+ support mean + l2norm in block 1024)
    ln_kernel<<<1025, 256, 0, stream>>>(yq, ln_g, ln_b, qg2, sg0, sgn);

    // 7. gates = qg2 @ W_ih'^T + b_ih + b_hh   (gate-compacted N=1024)
    gemm32<false, false, true><<<dim3(16, 32), 256, 0, stream>>>(
        qg2, W_ih, b_ih, b_hh, nullptr, gates, 1024, 1024, 256);

    // 8. LSTM step 1 (c0=0, h_r0=0 => gates==gates_base)
    lstm_step1_kernel<<<1024, 256, 0, stream>>>(gates, qg2, sg0, c1, hr);

    // 9. gates2 = gates_base + hr @ W_hh'^T   (in-place add)
    gemm32<false, true, true><<<dim3(16, 32), 256, 0, stream>>>(
        hr, W_hh, nullptr, nullptr, gates, gates, 1024, 1024, 512);

    // 10. LSTM step 2 + l2norm + dot(support_gn)
    lstm_step2_kernel<<<1024, 256, 0, stream>>>(gates, c1, qg2, sgn, out);
}

// Round 10
// 301.105 us; speedup vs baseline: 3.0259x; 1.1933x over previous
//
#include <hip/hip_runtime.h>
#include <math.h>

#define NEMB 200000
#define MM   200
#define KTOP 32
#define BB   1024
#define FEW  5
#define NROW 2058           // 2*BB + 2*FEW (row,half) tasks
#define NSLC 13             // ceil(200/16) 16-row slices

typedef short short8 __attribute__((ext_vector_type(8)));
typedef float floatx4 __attribute__((ext_vector_type(4)));

__device__ __forceinline__ float sigf(float x) { return 1.0f / (1.0f + expf(-x)); }

__device__ __forceinline__ unsigned short f2bf(float x) {   // RNE f32->bf16
    unsigned u = __float_as_uint(x);
    unsigned r = (u + 0x7FFF + ((u >> 16) & 1)) >> 16;
    return (unsigned short)r;
}

// ---------------------------------------------------------------------------
// K0: weight conversion fp32->bf16 (+ LSTM gate-compaction remap + bias fold)
// ---------------------------------------------------------------------------
__global__ __launch_bounds__(256) void convert_kernel(
    const float* __restrict__ se_w1, const float* __restrict__ se_w2,
    const float* __restrict__ W_ih, const float* __restrict__ W_hh,
    const float* __restrict__ b_ih, const float* __restrict__ b_hh,
    unsigned short* __restrict__ w1b, unsigned short* __restrict__ w2b,
    unsigned short* __restrict__ wihb, unsigned short* __restrict__ whhb,
    float* __restrict__ bias_c)
{
    int i = blockIdx.x * 256 + threadIdx.x;
    if (i < 131072) { w1b[i] = f2bf(se_w1[i]); return; }
    i -= 131072;
    if (i < 131072) { w2b[i] = f2bf(se_w2[i]); return; }
    i -= 131072;
    if (i < 262144) {           // W_ih compact: row n <- orig ((n>>8)<<9)|(n&255)
        int n = i >> 8, k = i & 255;
        int nb = ((n >> 8) << 9) | (n & 255);
        wihb[i] = f2bf(W_ih[(size_t)nb * 256 + k]); return;
    }
    i -= 262144;
    if (i < 524288) {
        int n = i >> 9, k = i & 511;
        int nb = ((n >> 8) << 9) | (n & 255);
        whhb[i] = f2bf(W_hh[(size_t)nb * 512 + k]); return;
    }
    i -= 524288;
    if (i < 1024) {
        int nb = ((i >> 8) << 9) | (i & 255);
        bias_c[i] = b_ih[nb] + b_hh[nb];
    }
}

// ---------------------------------------------------------------------------
// K1: sims — barrier-free, one wave per (row, slice-of-16-neighbors).
// ---------------------------------------------------------------------------
__global__ __launch_bounds__(256) void sims_kernel(
    const int* __restrict__ query, const int* __restrict__ support,
    const int* __restrict__ qlc, const int* __restrict__ qrc,
    const int* __restrict__ slc, const int* __restrict__ srrc,
    const float* __restrict__ emb, float* __restrict__ sims)
{
    const int wid  = (blockIdx.x * 256 + threadIdx.x) >> 6;
    const int lane = threadIdx.x & 63;
    const int quad = lane >> 2, ql = lane & 3;
    if (wid >= NROW * NSLC) return;

    const int rh = wid / NSLC, slice = wid - rh * NSLC;
    const int* conn; int eid;
    if (rh < BB)                 { conn = qlc + rh * (MM * 2);                 eid = query[rh * 2]; }
    else if (rh < 2 * BB)        { int b = rh - BB;        conn = qrc + b * (MM * 2);  eid = query[b * 2 + 1]; }
    else if (rh < 2 * BB + FEW)  { int r = rh - 2 * BB;    conn = slc + r * (MM * 2);  eid = support[r * 2]; }
    else                         { int r = rh - 2 * BB - FEW; conn = srrc + r * (MM * 2); eid = support[r * 2 + 1]; }

    const float4* cb = (const float4*)(emb + (size_t)eid * 128);
    float4 cr[8];
    #pragma unroll
    for (int i = 0; i < 8; ++i) cr[i] = cb[i * 4 + ql];
    float csq = 0.f;
    #pragma unroll
    for (int i = 0; i < 8; ++i)
        csq += cr[i].x * cr[i].x + cr[i].y * cr[i].y + cr[i].z * cr[i].z + cr[i].w * cr[i].w;
    csq += __shfl_xor(csq, 1, 4); csq += __shfl_xor(csq, 2, 4);
    const float cn = sqrtf(csq);

    const int  j = slice * 16 + quad;
    const bool v = j < MM;
    const int  rid = v ? conn[j * 2 + 1] : 0;
    const float4* eb = (const float4*)(emb + (size_t)rid * 128);
    float num = 0.f, sq = 0.f;
    #pragma unroll
    for (int i = 0; i < 8; ++i) {
        float4 e = eb[i * 4 + ql];
        num += cr[i].x * e.x + cr[i].y * e.y + cr[i].z * e.z + cr[i].w * e.w;
        sq  += e.x * e.x + e.y * e.y + e.z * e.z + e.w * e.w;
    }
    num += __shfl_xor(num, 1, 4); num += __shfl_xor(num, 2, 4);
    sq  += __shfl_xor(sq , 1, 4); sq  += __shfl_xor(sq , 2, 4);
    if (ql == 0 && v) sims[rh * MM + j] = num / fmaxf(cn * sqrtf(sq), 1e-8f);
}

// ---------------------------------------------------------------------------
// K2: rank (top-K, tie-break lower index, float4 scan) + mean gather -> avgbuf
// ---------------------------------------------------------------------------
__global__ __launch_bounds__(256) void rank_avg_kernel(
    const int* __restrict__ query, const int* __restrict__ support,
    const int* __restrict__ qlc, const int* __restrict__ qrc,
    const int* __restrict__ slc, const int* __restrict__ srrc,
    const float* __restrict__ emb, const float* __restrict__ sims,
    float* __restrict__ avgbuf)
{
    __shared__ float simsL[MM];
    __shared__ int   cids[MM];
    __shared__ int   selr[KTOP], sele[KTOP];
    __shared__ float partial[512];
    __shared__ int   nsel;

    const int t   = threadIdx.x;
    const int blk = blockIdx.x;

    const int* conn;
    if (blk < BB)                { conn = qlc + blk * (MM * 2); }
    else if (blk < 2 * BB)       { conn = qrc + (blk - BB) * (MM * 2); }
    else if (blk < 2 * BB + FEW) { conn = slc + (blk - 2 * BB) * (MM * 2); }
    else                         { conn = srrc + (blk - 2 * BB - FEW) * (MM * 2); }

    if (t < MM) { simsL[t] = sims[blk * MM + t]; cids[t] = conn[t * 2 + 1]; }
    if (t == 0) nsel = 0;
    __syncthreads();

    if (t < MM) {
        float st = simsL[t];
        int cnt = 0;
        #pragma unroll 2
        for (int j4 = 0; j4 < MM / 4; ++j4) {
            float4 s4 = *(const float4*)&simsL[j4 * 4];
            int jb = j4 * 4;
            cnt += (s4.x > st) || (s4.x == st && (jb + 0) < t);
            cnt += (s4.y > st) || (s4.y == st && (jb + 1) < t);
            cnt += (s4.z > st) || (s4.z == st && (jb + 2) < t);
            cnt += (s4.w > st) || (s4.w == st && (jb + 3) < t);
        }
        if (cnt < KTOP) {
            int p = atomicAdd(&nsel, 1);
            selr[p] = conn[t * 2 + 0];
            sele[p] = cids[t];
        }
    }
    __syncthreads();

    {
        const int slot = t & 127;
        const int hpar = t >> 7;
        const bool isEnt = slot >= 64;
        float2 acc = make_float2(0.f, 0.f);
        for (int s = hpar; s < KTOP; s += 2) {
            int rid = isEnt ? sele[s] : selr[s];
            float2 v = ((const float2*)(emb + (size_t)rid * 128))[slot & 63];
            acc.x += v.x; acc.y += v.y;
        }
        ((float2*)partial)[t] = acc;
    }
    __syncthreads();
    if (t < 128) {
        float2 a = ((float2*)partial)[t];
        float2 b = ((float2*)partial)[t + 128];
        ((float2*)(avgbuf + (size_t)blk * 256))[t] =
            make_float2((a.x + b.x) * (1.0f / KTOP), (a.y + b.y) * (1.0f / KTOP));
    }
}

// ---------------------------------------------------------------------------
// K3: GCN matvec as fp32 GEMM -> qn2 (fp32) + qn2_bf (bf16)
// ---------------------------------------------------------------------------
__global__ __launch_bounds__(256) void gcn_gemm_kernel(
    const float* __restrict__ A, const float* __restrict__ W,
    const float* __restrict__ gcn_bias, const float* __restrict__ gcn_b,
    float* __restrict__ qn2, unsigned short* __restrict__ qn2b)
{
    __shared__ float As[16][68];
    __shared__ float Ws[16][68];
    const int t  = threadIdx.x;
    const int bm = blockIdx.y * 64, bn = blockIdx.x * 64;
    const int tx = t & 15, ty = t >> 4;
    const int lrow = t >> 2, lk4 = (t & 3) * 4;

    const float* Ap = A + (size_t)(bm + lrow) * 256 + lk4;
    const float* Wp = W + (size_t)(bn + lrow) * 256 + lk4;

    float acc[4][4] = {};
    for (int k0 = 0; k0 < 256; k0 += 16) {
        float4 av = *(const float4*)(Ap + k0);
        float4 wv = *(const float4*)(Wp + k0);
        __syncthreads();
        As[lk4 + 0][lrow] = av.x; As[lk4 + 1][lrow] = av.y;
        As[lk4 + 2][lrow] = av.z; As[lk4 + 3][lrow] = av.w;
        Ws[lk4 + 0][lrow] = wv.x; Ws[lk4 + 1][lrow] = wv.y;
        Ws[lk4 + 2][lrow] = wv.z; Ws[lk4 + 3][lrow] = wv.w;
        __syncthreads();
        #pragma unroll
        for (int kk = 0; kk < 16; ++kk) {
            float4 a = *(const float4*)&As[kk][ty * 4];
            float4 b = *(const float4*)&Ws[kk][tx * 4];
            acc[0][0] += a.x * b.x; acc[0][1] += a.x * b.y; acc[0][2] += a.x * b.z; acc[0][3] += a.x * b.w;
            acc[1][0] += a.y * b.x; acc[1][1] += a.y * b.y; acc[1][2] += a.y * b.z; acc[1][3] += a.y * b.w;
            acc[2][0] += a.z * b.x; acc[2][1] += a.z * b.y; acc[2][2] += a.z * b.z; acc[2][3] += a.z * b.w;
            acc[3][0] += a.w * b.x; acc[3][1] += a.w * b.y; acc[3][2] += a.w * b.z; acc[3][3] += a.w * b.w;
        }
    }

    const int n0 = bn + tx * 4;
    float4 bv = *(const float4*)(gcn_bias + n0);
    float4 b2 = *(const float4*)(gcn_b + n0);
    bv.x += b2.x; bv.y += b2.y; bv.z += b2.z; bv.w += b2.w;

    #pragma unroll
    for (int i = 0; i < 4; ++i) {
        int tk = bm + ty * 4 + i;
        if (tk >= NROW) continue;
        int row_out, half;
        if (tk < BB)                { row_out = tk;                 half = 0; }
        else if (tk < 2 * BB)       { row_out = tk - BB;            half = 1; }
        else if (tk < 2 * BB + FEW) { row_out = BB + tk - 2 * BB;   half = 0; }
        else                        { row_out = BB + tk - 2 * BB - FEW; half = 1; }
        float4 v = make_float4(tanhf(acc[i][0] + bv.x), tanhf(acc[i][1] + bv.y),
                               tanhf(acc[i][2] + bv.z), tanhf(acc[i][3] + bv.w));
        size_t base = (size_t)row_out * 256 + half * 128 + n0;
        *(float4*)(qn2 + base) = v;
        ushort4 u = make_ushort4(f2bf(v.x), f2bf(v.y), f2bf(v.z), f2bf(v.w));
        *(ushort4*)(qn2b + base) = u;
    }
}

// ---------------------------------------------------------------------------
// MFMA bf16 GEMM: C[M,N](fp32 or relu->bf16) = A_bf[M,K] @ W_bf[N,K]^T
// (+bias fp32)(+add fp32). 64x64 block tile, 4 waves, 16x16x32 mfma.
// Layouts (m89/m120-verified): A frag m=lane&15,k=quad*8+j; B frag from W
// row n=lane&15 (B^T pattern); C/D col=lane&15,row=quad*4+reg.
// ---------------------------------------------------------------------------
template <bool RELU_BF_OUT, bool HAS_ADD, bool HAS_BIAS>
__global__ __launch_bounds__(256) void mfma_gemm(
    const unsigned short* __restrict__ Abf, const unsigned short* __restrict__ Wbf,
    const float* __restrict__ bias, const float* __restrict__ add,
    float* __restrict__ Cf, unsigned short* __restrict__ Cbf,
    int N_, int K_)
{
    __shared__ short Asl[64][40];   // +8 pad: 2-way LDS conflicts only (free)
    __shared__ short Wsl[64][40];
    const int t = threadIdx.x;
    const int w = t >> 6, l = t & 63;
    const int l15 = l & 15, q = l >> 4;
    const int bm = blockIdx.y * 64, bn = blockIdx.x * 64;

    const int srow = t >> 2, skoff = (t & 3) * 8;
    const unsigned short* Ap = Abf + (size_t)(bm + srow) * K_ + skoff;
    const unsigned short* Wp = Wbf + (size_t)(bn + srow) * K_ + skoff;

    floatx4 acc[4];
    #pragma unroll
    for (int jf = 0; jf < 4; ++jf) acc[jf] = (floatx4){0.f, 0.f, 0.f, 0.f};

    for (int k0 = 0; k0 < K_; k0 += 32) {
        short8 av = *(const short8*)(Ap + k0);
        short8 wv = *(const short8*)(Wp + k0);
        __syncthreads();
        *(short8*)&Asl[srow][skoff] = av;
        *(short8*)&Wsl[srow][skoff] = wv;
        __syncthreads();
        short8 a = *(const short8*)&Asl[w * 16 + l15][q * 8];
        #pragma unroll
        for (int jf = 0; jf < 4; ++jf) {
            short8 b = *(const short8*)&Wsl[jf * 16 + l15][q * 8];
            acc[jf] = __builtin_amdgcn_mfma_f32_16x16x32_bf16(a, b, acc[jf], 0, 0, 0);
        }
    }

    #pragma unroll
    for (int jf = 0; jf < 4; ++jf) {
        const int col = bn + jf * 16 + l15;
        float bv = HAS_BIAS ? bias[col] : 0.f;
        #pragma unroll
        for (int r = 0; r < 4; ++r) {
            const int m = bm + w * 16 + q * 4 + r;
            float v = acc[jf][r] + bv;
            if (HAS_ADD) v += add[(size_t)m * N_ + col];
            if (RELU_BF_OUT) Cbf[(size_t)m * N_ + col] = f2bf(fmaxf(v, 0.f));
            else             Cf [(size_t)m * N_ + col] = v;
        }
    }
}

// ---------------------------------------------------------------------------
// LayerNorm per row (+ qg2_bf write); block 1024: support rows + mean + l2norm
// ---------------------------------------------------------------------------
__global__ __launch_bounds__(256) void ln_kernel(
    const float* __restrict__ y, const float* __restrict__ g,
    const float* __restrict__ beta, float* __restrict__ out,
    unsigned short* __restrict__ outb, float* __restrict__ sg0,
    float* __restrict__ sgn)
{
    __shared__ float rs[4], rq[4];
    const int t = threadIdx.x;
    const int lane = t & 63, wave = t >> 6;

    if (blockIdx.x < 1024) {
        const int row = blockIdx.x;
        float v = y[row * 256 + t];
        float s = v, q = v * v;
        #pragma unroll
        for (int i = 32; i >= 1; i >>= 1) { s += __shfl_xor(s, i, 64); q += __shfl_xor(q, i, 64); }
        if (lane == 0) { rs[wave] = s; rq[wave] = q; }
        __syncthreads();
        float tot  = rs[0] + rs[1] + rs[2] + rs[3];
        float totq = rq[0] + rq[1] + rq[2] + rq[3];
        float mu  = tot * (1.0f / 256.0f);
        float var = fmaxf(totq * (1.0f / 256.0f) - mu * mu, 0.0f);
        float o = g[t] * (v - mu) / sqrtf(var + 1e-5f) + beta[t];
        out[row * 256 + t]  = o;
        outb[row * 256 + t] = f2bf(o);
    } else {
        float acc = 0.f;
        for (int r = 0; r < FEW; ++r) {
            __syncthreads();
            float v = y[(BB + r) * 256 + t];
            float s = v, q = v * v;
            #pragma unroll
            for (int i = 32; i >= 1; i >>= 1) { s += __shfl_xor(s, i, 64); q += __shfl_xor(q, i, 64); }
            if (lane == 0) { rs[wave] = s; rq[wave] = q; }
            __syncthreads();
            float tot  = rs[0] + rs[1] + rs[2] + rs[3];
            float totq = rq[0] + rq[1] + rq[2] + rq[3];
            float mu  = tot * (1.0f / 256.0f);
            float var = fmaxf(totq * (1.0f / 256.0f) - mu * mu, 0.0f);
            acc += g[t] * (v - mu) / sqrtf(var + 1e-5f) + beta[t];
        }
        acc *= (1.0f / FEW);
        sg0[t] = acc;
        __syncthreads();
        float q = acc * acc;
        #pragma unroll
        for (int i = 32; i >= 1; i >>= 1) q += __shfl_xor(q, i, 64);
        if (lane == 0) rq[wave] = q;
        __syncthreads();
        float nrm = sqrtf(rq[0] + rq[1] + rq[2] + rq[3]);
        sgn[t] = acc / fmaxf(nrm, 1e-12f);
    }
}

// gates compact layout: [0:256)=i [256:512)=f [512:768)=g [768:1024)=o
__global__ __launch_bounds__(256) void lstm_step1_kernel(
    const float* __restrict__ gates, const float* __restrict__ qg,
    const float* __restrict__ sg0, float* __restrict__ c1,
    unsigned short* __restrict__ hrb)
{
    const int row = blockIdx.x, t = threadIdx.x;
    const float* gr = gates + row * 1024;
    float iv = gr[t], gv = gr[512 + t], ov = gr[768 + t];
    float cv = sigf(iv) * tanhf(gv);          // c0 = 0 => f-term drops
    c1[row * 256 + t] = cv;
    float hf = sigf(ov) * tanhf(cv);
    hrb[row * 512 + t]       = f2bf(qg[row * 256 + t] + hf);  // h1
    hrb[row * 512 + 256 + t] = f2bf(sg0[t]);                  // r (attn == 1)
}

__global__ __launch_bounds__(256) void lstm_step2_kernel(
    const float* __restrict__ gates, const float* __restrict__ c1,
    const float* __restrict__ qg, const float* __restrict__ sgn,
    float* __restrict__ outv)
{
    __shared__ float rn[4], rd[4];
    const int row = blockIdx.x, t = threadIdx.x;
    const int lane = t & 63, wave = t >> 6;
    const float* gr = gates + row * 1024;
    float iv = gr[t], fv = gr[256 + t], gv = gr[512 + t], ov = gr[768 + t];
    float cv = sigf(fv) * c1[row * 256 + t] + sigf(iv) * tanhf(gv);
    float h2 = qg[row * 256 + t] + sigf(ov) * tanhf(cv);
    float nn = h2 * h2, dd = h2 * sgn[t];
    #pragma unroll
    for (int i = 32; i >= 1; i >>= 1) { nn += __shfl_xor(nn, i, 64); dd += __shfl_xor(dd, i, 64); }
    if (lane == 0) { rn[wave] = nn; rd[wave] = dd; }
    __syncthreads();
    if (t == 0) {
        float n2 = rn[0] + rn[1] + rn[2] + rn[3];
        float dt = rd[0] + rd[1] + rd[2] + rd[3];
        outv[row] = dt / fmaxf(sqrtf(n2), 1e-12f);
    }
}

extern "C" void kernel_launch(void* const* d_in, const int* in_sizes, int n_in,
                              void* d_out, int out_size, void* d_ws, size_t ws_size,
                              hipStream_t stream)
{
    const int*   query    = (const int*)d_in[0];
    const int*   support  = (const int*)d_in[1];
    const int*   q_l_conn = (const int*)d_in[2];
    const int*   q_r_conn = (const int*)d_in[4];
    const int*   s_l_conn = (const int*)d_in[6];
    const int*   s_r_conn = (const int*)d_in[8];
    const float* emb      = (const float*)d_in[10];
    const float* gcn_W    = (const float*)d_in[11];
    const float* gcn_bias = (const float*)d_in[12];
    const float* gcn_b    = (const float*)d_in[13];
    const float* se_w1    = (const float*)d_in[14];
    const float* se_b1    = (const float*)d_in[15];
    const float* se_w2    = (const float*)d_in[16];
    const float* se_b2    = (const float*)d_in[17];
    const float* ln_g     = (const float*)d_in[18];
    const float* ln_b     = (const float*)d_in[19];
    const float* W_ih     = (const float*)d_in[20];
    const float* W_hh     = (const float*)d_in[21];
    const float* b_ih     = (const float*)d_in[22];
    const float* b_hh     = (const float*)d_in[23];
    float* out = (float*)d_out;

    float* ws     = (float*)d_ws;
    float* qn2    = ws;                    // 1088*256 f
    float* yq     = qn2    + 1088 * 256;   // 1088*256 f
    float* qg2    = yq     + 1088 * 256;   // 1088*256 f
    float* sg0    = qg2    + 1088 * 256;   // 256
    float* sgn    = sg0    + 256;          // 256
    float* gates  = sgn    + 256;          // 1024*1024 f
    float* c1     = gates  + 1024 * 1024;  // 1024*256 f
    float* avgbuf = c1     + 1024 * 256;   // 2112*256 f
    float* bias_c = avgbuf + 2112 * 256;   // 1024 f
    unsigned short* qn2b = (unsigned short*)(bias_c + 1024);  // 1088*256 sh
    unsigned short* h1b  = qn2b + 1088 * 256;                 // 1088*512 sh
    unsigned short* qg2b = h1b  + 1088 * 512;                 // 1024*256 sh
    unsigned short* hrb  = qg2b + 1024 * 256;                 // 1024*512 sh
    unsigned short* w1b  = hrb  + 1024 * 512;                 // 512*256 sh
    unsigned short* w2b  = w1b  + 512 * 256;                  // 256*512 sh
    unsigned short* wihb = w2b  + 256 * 512;                  // 1024*256 sh
    unsigned short* whhb = wihb + 1024 * 256;                 // 1024*512 sh
    float* sims = gates;   // overlay: sims (411.6k f) dies before gates written

    // 0. weight conversion (independent; fills pipeline head)
    convert_kernel<<<4100, 256, 0, stream>>>(
        se_w1, se_w2, W_ih, W_hh, b_ih, b_hh, w1b, w2b, wihb, whhb, bias_c);

    // 1. sims (barrier-free max-MLP gather)
    const int nwaves = NROW * NSLC;                       // 26754
    sims_kernel<<<(nwaves + 3) / 4, 256, 0, stream>>>(
        query, support, q_l_conn, q_r_conn, s_l_conn, s_r_conn, emb, sims);

    // 2. top-K rank + mean gather -> avgbuf
    rank_avg_kernel<<<NROW, 256, 0, stream>>>(
        query, support, q_l_conn, q_r_conn, s_l_conn, s_r_conn,
        emb, sims, avgbuf);

    // 3. GCN matvec GEMM -> qn2 (f32 + bf16)
    gcn_gemm_kernel<<<dim3(2, 33), 256, 0, stream>>>(
        avgbuf, gcn_W, gcn_bias, gcn_b, qn2, qn2b);

    // 4. SE GEMM1 (MFMA): h1_bf = bf16(relu(qn2 @ w1^T + b1))
    mfma_gemm<true, false, true><<<dim3(8, 17), 256, 0, stream>>>(
        qn2b, w1b, se_b1, nullptr, nullptr, h1b, 512, 256);

    // 5. SE GEMM2 (MFMA): yq = h1 @ w2^T + b2 + qn2
    mfma_gemm<false, true, true><<<dim3(4, 17), 256, 0, stream>>>(
        h1b, w2b, se_b2, qn2, yq, nullptr, 256, 512);

    // 6. LayerNorm -> qg2 (f32 + bf16) (+ support mean + l2norm in block 1024)
    ln_kernel<<<1025, 256, 0, stream>>>(yq, ln_g, ln_b, qg2, qg2b, sg0, sgn);

    // 7. gates = qg2 @ W_ih'^T + (b_ih+b_hh)  (MFMA, gate-compacted)
    mfma_gemm<false, false, true><<<dim3(16, 16), 256, 0, stream>>>(
        qg2b, wihb, bias_c, nullptr, gates, nullptr, 1024, 256);

    // 8. LSTM step 1 (c0=0, h_r0=0) -> c1, hr_bf
    lstm_step1_kernel<<<1024, 256, 0, stream>>>(gates, qg2, sg0, c1, hrb);

    // 9. gates += hr @ W_hh'^T  (MFMA, in-place add)
    mfma_gemm<false, true, false><<<dim3(16, 16), 256, 0, stream>>>(
        hrb, whhb, nullptr, gates, gates, nullptr, 1024, 512);

    // 10. LSTM step 2 + l2norm + dot(support_gn)
    lstm_step2_kernel<<<1024, 256, 0, stream>>>(gates, c1, qg2, sgn, out);
}

// Round 12
// 299.433 us; speedup vs baseline: 3.0427x; 1.0056x over previous
//
#include <hip/hip_runtime.h>
#include <math.h>

#define NEMB 200000
#define MM   200
#define KTOP 32
#define BB   1024
#define FEW  5
#define NROW 2058           // 2*BB + 2*FEW (row,half) tasks
#define NSLC 13             // ceil(200/16) 16-row slices

typedef short short8 __attribute__((ext_vector_type(8)));
typedef float floatx4 __attribute__((ext_vector_type(4)));

__device__ __forceinline__ float sigf(float x) { return 1.0f / (1.0f + expf(-x)); }

__device__ __forceinline__ unsigned short f2bf(float x) {   // RNE f32->bf16
    unsigned u = __float_as_uint(x);
    unsigned r = (u + 0x7FFF + ((u >> 16) & 1)) >> 16;
    return (unsigned short)r;
}

// ---------------------------------------------------------------------------
// K0: weight conversion fp32->bf16 (+ LSTM gate-compaction remap + bias fold)
// NOTE: emb table stays fp32 — bf16 sims perturbs top-K selection (round 11:
// absmax 3.5e-2). Cosine-sim spacing near rank 32 (~0.002) < bf16 noise.
// ---------------------------------------------------------------------------
__global__ __launch_bounds__(256) void convert_kernel(
    const float* __restrict__ se_w1, const float* __restrict__ se_w2,
    const float* __restrict__ W_ih, const float* __restrict__ W_hh,
    const float* __restrict__ b_ih, const float* __restrict__ b_hh,
    unsigned short* __restrict__ w1b, unsigned short* __restrict__ w2b,
    unsigned short* __restrict__ wihb, unsigned short* __restrict__ whhb,
    float* __restrict__ bias_c)
{
    int i = blockIdx.x * 256 + threadIdx.x;
    if (i < 131072) { w1b[i] = f2bf(se_w1[i]); return; }
    i -= 131072;
    if (i < 131072) { w2b[i] = f2bf(se_w2[i]); return; }
    i -= 131072;
    if (i < 262144) {           // W_ih compact: row n <- orig ((n>>8)<<9)|(n&255)
        int n = i >> 8, k = i & 255;
        int nb = ((n >> 8) << 9) | (n & 255);
        wihb[i] = f2bf(W_ih[(size_t)nb * 256 + k]); return;
    }
    i -= 262144;
    if (i < 524288) {
        int n = i >> 9, k = i & 511;
        int nb = ((n >> 8) << 9) | (n & 255);
        whhb[i] = f2bf(W_hh[(size_t)nb * 512 + k]); return;
    }
    i -= 524288;
    if (i < 1024) {
        int nb = ((i >> 8) << 9) | (i & 255);
        bias_c[i] = b_ih[nb] + b_hh[nb];
    }
}

// ---------------------------------------------------------------------------
// K1: sims — barrier-free, one wave per (row, slice-of-16-neighbors). fp32.
// ---------------------------------------------------------------------------
__global__ __launch_bounds__(256) void sims_kernel(
    const int* __restrict__ query, const int* __restrict__ support,
    const int* __restrict__ qlc, const int* __restrict__ qrc,
    const int* __restrict__ slc, const int* __restrict__ srrc,
    const float* __restrict__ emb, float* __restrict__ sims)
{
    const int wid  = (blockIdx.x * 256 + threadIdx.x) >> 6;
    const int lane = threadIdx.x & 63;
    const int quad = lane >> 2, ql = lane & 3;
    if (wid >= NROW * NSLC) return;

    const int rh = wid / NSLC, slice = wid - rh * NSLC;
    const int* conn; int eid;
    if (rh < BB)                 { conn = qlc + rh * (MM * 2);                 eid = query[rh * 2]; }
    else if (rh < 2 * BB)        { int b = rh - BB;        conn = qrc + b * (MM * 2);  eid = query[b * 2 + 1]; }
    else if (rh < 2 * BB + FEW)  { int r = rh - 2 * BB;    conn = slc + r * (MM * 2);  eid = support[r * 2]; }
    else                         { int r = rh - 2 * BB - FEW; conn = srrc + r * (MM * 2); eid = support[r * 2 + 1]; }

    const float4* cb = (const float4*)(emb + (size_t)eid * 128);
    float4 cr[8];
    #pragma unroll
    for (int i = 0; i < 8; ++i) cr[i] = cb[i * 4 + ql];
    float csq = 0.f;
    #pragma unroll
    for (int i = 0; i < 8; ++i)
        csq += cr[i].x * cr[i].x + cr[i].y * cr[i].y + cr[i].z * cr[i].z + cr[i].w * cr[i].w;
    csq += __shfl_xor(csq, 1, 4); csq += __shfl_xor(csq, 2, 4);
    const float cn = sqrtf(csq);

    const int  j = slice * 16 + quad;
    const bool v = j < MM;
    const int  rid = v ? conn[j * 2 + 1] : 0;
    const float4* eb = (const float4*)(emb + (size_t)rid * 128);
    float num = 0.f, sq = 0.f;
    #pragma unroll
    for (int i = 0; i < 8; ++i) {
        float4 e = eb[i * 4 + ql];
        num += cr[i].x * e.x + cr[i].y * e.y + cr[i].z * e.z + cr[i].w * e.w;
        sq  += e.x * e.x + e.y * e.y + e.z * e.z + e.w * e.w;
    }
    num += __shfl_xor(num, 1, 4); num += __shfl_xor(num, 2, 4);
    sq  += __shfl_xor(sq , 1, 4); sq  += __shfl_xor(sq , 2, 4);
    if (ql == 0 && v) sims[rh * MM + j] = num / fmaxf(cn * sqrtf(sq), 1e-8f);
}

// ---------------------------------------------------------------------------
// K2: rank (top-K, tie-break lower index, float4 scan) + mean gather -> avgbuf
// ---------------------------------------------------------------------------
__global__ __launch_bounds__(256) void rank_avg_kernel(
    const int* __restrict__ query, const int* __restrict__ support,
    const int* __restrict__ qlc, const int* __restrict__ qrc,
    const int* __restrict__ slc, const int* __restrict__ srrc,
    const float* __restrict__ emb, const float* __restrict__ sims,
    float* __restrict__ avgbuf)
{
    __shared__ float simsL[MM];
    __shared__ int   cids[MM];
    __shared__ int   selr[KTOP], sele[KTOP];
    __shared__ float partial[512];
    __shared__ int   nsel;

    const int t   = threadIdx.x;
    const int blk = blockIdx.x;

    const int* conn;
    if (blk < BB)                { conn = qlc + blk * (MM * 2); }
    else if (blk < 2 * BB)       { conn = qrc + (blk - BB) * (MM * 2); }
    else if (blk < 2 * BB + FEW) { conn = slc + (blk - 2 * BB) * (MM * 2); }
    else                         { conn = srrc + (blk - 2 * BB - FEW) * (MM * 2); }

    if (t < MM) { simsL[t] = sims[blk * MM + t]; cids[t] = conn[t * 2 + 1]; }
    if (t == 0) nsel = 0;
    __syncthreads();

    if (t < MM) {
        float st = simsL[t];
        int cnt = 0;
        #pragma unroll 2
        for (int j4 = 0; j4 < MM / 4; ++j4) {
            float4 s4 = *(const float4*)&simsL[j4 * 4];
            int jb = j4 * 4;
            cnt += (s4.x > st) || (s4.x == st && (jb + 0) < t);
            cnt += (s4.y > st) || (s4.y == st && (jb + 1) < t);
            cnt += (s4.z > st) || (s4.z == st && (jb + 2) < t);
            cnt += (s4.w > st) || (s4.w == st && (jb + 3) < t);
        }
        if (cnt < KTOP) {
            int p = atomicAdd(&nsel, 1);
            selr[p] = conn[t * 2 + 0];
            sele[p] = cids[t];
        }
    }
    __syncthreads();

    {
        const int slot = t & 127;
        const int hpar = t >> 7;
        const bool isEnt = slot >= 64;
        float2 acc = make_float2(0.f, 0.f);
        for (int s = hpar; s < KTOP; s += 2) {
            int rid = isEnt ? sele[s] : selr[s];
            float2 v = ((const float2*)(emb + (size_t)rid * 128))[slot & 63];
            acc.x += v.x; acc.y += v.y;
        }
        ((float2*)partial)[t] = acc;
    }
    __syncthreads();
    if (t < 128) {
        float2 a = ((float2*)partial)[t];
        float2 b = ((float2*)partial)[t + 128];
        ((float2*)(avgbuf + (size_t)blk * 256))[t] =
            make_float2((a.x + b.x) * (1.0f / KTOP), (a.y + b.y) * (1.0f / KTOP));
    }
}

// ---------------------------------------------------------------------------
// K3: GCN matvec as fp32 GEMM -> qn2 (fp32) + qn2_bf (bf16)
// ---------------------------------------------------------------------------
__global__ __launch_bounds__(256) void gcn_gemm_kernel(
    const float* __restrict__ A, const float* __restrict__ W,
    const float* __restrict__ gcn_bias, const float* __restrict__ gcn_b,
    float* __restrict__ qn2, unsigned short* __restrict__ qn2b)
{
    __shared__ float As[16][68];
    __shared__ float Ws[16][68];
    const int t  = threadIdx.x;
    const int bm = blockIdx.y * 64, bn = blockIdx.x * 64;
    const int tx = t & 15, ty = t >> 4;
    const int lrow = t >> 2, lk4 = (t & 3) * 4;

    const float* Ap = A + (size_t)(bm + lrow) * 256 + lk4;
    const float* Wp = W + (size_t)(bn + lrow) * 256 + lk4;

    float acc[4][4] = {};
    for (int k0 = 0; k0 < 256; k0 += 16) {
        float4 av = *(const float4*)(Ap + k0);
        float4 wv = *(const float4*)(Wp + k0);
        __syncthreads();
        As[lk4 + 0][lrow] = av.x; As[lk4 + 1][lrow] = av.y;
        As[lk4 + 2][lrow] = av.z; As[lk4 + 3][lrow] = av.w;
        Ws[lk4 + 0][lrow] = wv.x; Ws[lk4 + 1][lrow] = wv.y;
        Ws[lk4 + 2][lrow] = wv.z; Ws[lk4 + 3][lrow] = wv.w;
        __syncthreads();
        #pragma unroll
        for (int kk = 0; kk < 16; ++kk) {
            float4 a = *(const float4*)&As[kk][ty * 4];
            float4 b = *(const float4*)&Ws[kk][tx * 4];
            acc[0][0] += a.x * b.x; acc[0][1] += a.x * b.y; acc[0][2] += a.x * b.z; acc[0][3] += a.x * b.w;
            acc[1][0] += a.y * b.x; acc[1][1] += a.y * b.y; acc[1][2] += a.y * b.z; acc[1][3] += a.y * b.w;
            acc[2][0] += a.z * b.x; acc[2][1] += a.z * b.y; acc[2][2] += a.z * b.z; acc[2][3] += a.z * b.w;
            acc[3][0] += a.w * b.x; acc[3][1] += a.w * b.y; acc[3][2] += a.w * b.z; acc[3][3] += a.w * b.w;
        }
    }

    const int n0 = bn + tx * 4;
    float4 bv = *(const float4*)(gcn_bias + n0);
    float4 b2 = *(const float4*)(gcn_b + n0);
    bv.x += b2.x; bv.y += b2.y; bv.z += b2.z; bv.w += b2.w;

    #pragma unroll
    for (int i = 0; i < 4; ++i) {
        int tk = bm + ty * 4 + i;
        if (tk >= NROW) continue;
        int row_out, half;
        if (tk < BB)                { row_out = tk;                 half = 0; }
        else if (tk < 2 * BB)       { row_out = tk - BB;            half = 1; }
        else if (tk < 2 * BB + FEW) { row_out = BB + tk - 2 * BB;   half = 0; }
        else                        { row_out = BB + tk - 2 * BB - FEW; half = 1; }
        float4 v = make_float4(tanhf(acc[i][0] + bv.x), tanhf(acc[i][1] + bv.y),
                               tanhf(acc[i][2] + bv.z), tanhf(acc[i][3] + bv.w));
        size_t base = (size_t)row_out * 256 + half * 128 + n0;
        *(float4*)(qn2 + base) = v;
        ushort4 u = make_ushort4(f2bf(v.x), f2bf(v.y), f2bf(v.z), f2bf(v.w));
        *(ushort4*)(qn2b + base) = u;
    }
}

// ---------------------------------------------------------------------------
// MFMA bf16 GEMM: C[M,N](fp32 or relu->bf16) = A_bf[M,K] @ W_bf[N,K]^T
// (+bias fp32)(+add fp32). 64x64 block tile, 4 waves, 16x16x32 mfma.
// ---------------------------------------------------------------------------
template <bool RELU_BF_OUT, bool HAS_ADD, bool HAS_BIAS>
__global__ __launch_bounds__(256) void mfma_gemm(
    const unsigned short* __restrict__ Abf, const unsigned short* __restrict__ Wbf,
    const float* __restrict__ bias, const float* __restrict__ add,
    float* __restrict__ Cf, unsigned short* __restrict__ Cbf,
    int N_, int K_)
{
    __shared__ short Asl[64][40];   // +8 pad: 2-way LDS conflicts only (free)
    __shared__ short Wsl[64][40];
    const int t = threadIdx.x;
    const int w = t >> 6, l = t & 63;
    const int l15 = l & 15, q = l >> 4;
    const int bm = blockIdx.y * 64, bn = blockIdx.x * 64;

    const int srow = t >> 2, skoff = (t & 3) * 8;
    const unsigned short* Ap = Abf + (size_t)(bm + srow) * K_ + skoff;
    const unsigned short* Wp = Wbf + (size_t)(bn + srow) * K_ + skoff;

    floatx4 acc[4];
    #pragma unroll
    for (int jf = 0; jf < 4; ++jf) acc[jf] = (floatx4){0.f, 0.f, 0.f, 0.f};

    for (int k0 = 0; k0 < K_; k0 += 32) {
        short8 av = *(const short8*)(Ap + k0);
        short8 wv = *(const short8*)(Wp + k0);
        __syncthreads();
        *(short8*)&Asl[srow][skoff] = av;
        *(short8*)&Wsl[srow][skoff] = wv;
        __syncthreads();
        short8 a = *(const short8*)&Asl[w * 16 + l15][q * 8];
        #pragma unroll
        for (int jf = 0; jf < 4; ++jf) {
            short8 b = *(const short8*)&Wsl[jf * 16 + l15][q * 8];
            acc[jf] = __builtin_amdgcn_mfma_f32_16x16x32_bf16(a, b, acc[jf], 0, 0, 0);
        }
    }

    #pragma unroll
    for (int jf = 0; jf < 4; ++jf) {
        const int col = bn + jf * 16 + l15;
        float bv = HAS_BIAS ? bias[col] : 0.f;
        #pragma unroll
        for (int r = 0; r < 4; ++r) {
            const int m = bm + w * 16 + q * 4 + r;
            float v = acc[jf][r] + bv;
            if (HAS_ADD) v += add[(size_t)m * N_ + col];
            if (RELU_BF_OUT) Cbf[(size_t)m * N_ + col] = f2bf(fmaxf(v, 0.f));
            else             Cf [(size_t)m * N_ + col] = v;
        }
    }
}

// ---------------------------------------------------------------------------
// LayerNorm per row (+ qg2_bf write); block 1024: support rows + mean + l2norm
// ---------------------------------------------------------------------------
__global__ __launch_bounds__(256) void ln_kernel(
    const float* __restrict__ y, const float* __restrict__ g,
    const float* __restrict__ beta, float* __restrict__ out,
    unsigned short* __restrict__ outb, float* __restrict__ sg0,
    float* __restrict__ sgn)
{
    __shared__ float rs[4], rq[4];
    const int t = threadIdx.x;
    const int lane = t & 63, wave = t >> 6;

    if (blockIdx.x < 1024) {
        const int row = blockIdx.x;
        float v = y[row * 256 + t];
        float s = v, q = v * v;
        #pragma unroll
        for (int i = 32; i >= 1; i >>= 1) { s += __shfl_xor(s, i, 64); q += __shfl_xor(q, i, 64); }
        if (lane == 0) { rs[wave] = s; rq[wave] = q; }
        __syncthreads();
        float tot  = rs[0] + rs[1] + rs[2] + rs[3];
        float totq = rq[0] + rq[1] + rq[2] + rq[3];
        float mu  = tot * (1.0f / 256.0f);
        float var = fmaxf(totq * (1.0f / 256.0f) - mu * mu, 0.0f);
        float o = g[t] * (v - mu) / sqrtf(var + 1e-5f) + beta[t];
        out[row * 256 + t]  = o;
        outb[row * 256 + t] = f2bf(o);
    } else {
        float acc = 0.f;
        for (int r = 0; r < FEW; ++r) {
            __syncthreads();
            float v = y[(BB + r) * 256 + t];
            float s = v, q = v * v;
            #pragma unroll
            for (int i = 32; i >= 1; i >>= 1) { s += __shfl_xor(s, i, 64); q += __shfl_xor(q, i, 64); }
            if (lane == 0) { rs[wave] = s; rq[wave] = q; }
            __syncthreads();
            float tot  = rs[0] + rs[1] + rs[2] + rs[3];
            float totq = rq[0] + rq[1] + rq[2] + rq[3];
            float mu  = tot * (1.0f / 256.0f);
            float var = fmaxf(totq * (1.0f / 256.0f) - mu * mu, 0.0f);
            acc += g[t] * (v - mu) / sqrtf(var + 1e-5f) + beta[t];
        }
        acc *= (1.0f / FEW);
        sg0[t] = acc;
        __syncthreads();
        float q = acc * acc;
        #pragma unroll
        for (int i = 32; i >= 1; i >>= 1) q += __shfl_xor(q, i, 64);
        if (lane == 0) rq[wave] = q;
        __syncthreads();
        float nrm = sqrtf(rq[0] + rq[1] + rq[2] + rq[3]);
        sgn[t] = acc / fmaxf(nrm, 1e-12f);
    }
}

// gates compact layout: [0:256)=i [256:512)=f [512:768)=g [768:1024)=o
__global__ __launch_bounds__(256) void lstm_step1_kernel(
    const float* __restrict__ gates, const float* __restrict__ qg,
    const float* __restrict__ sg0, float* __restrict__ c1,
    unsigned short* __restrict__ hrb)
{
    const int row = blockIdx.x, t = threadIdx.x;
    const float* gr = gates + row * 1024;
    float iv = gr[t], gv = gr[512 + t], ov = gr[768 + t];
    float cv = sigf(iv) * tanhf(gv);          // c0 = 0 => f-term drops
    c1[row * 256 + t] = cv;
    float hf = sigf(ov) * tanhf(cv);
    hrb[row * 512 + t]       = f2bf(qg[row * 256 + t] + hf);  // h1
    hrb[row * 512 + 256 + t] = f2bf(sg0[t]);                  // r (attn == 1)
}

__global__ __launch_bounds__(256) void lstm_step2_kernel(
    const float* __restrict__ gates, const float* __restrict__ c1,
    const float* __restrict__ qg, const float* __restrict__ sgn,
    float* __restrict__ outv)
{
    __shared__ float rn[4], rd[4];
    const int row = blockIdx.x, t = threadIdx.x;
    const int lane = t & 63, wave = t >> 6;
    const float* gr = gates + row * 1024;
    float iv = gr[t], fv = gr[256 + t], gv = gr[512 + t], ov = gr[768 + t];
    float cv = sigf(fv) * c1[row * 256 + t] + sigf(iv) * tanhf(gv);
    float h2 = qg[row * 256 + t] + sigf(ov) * tanhf(cv);
    float nn = h2 * h2, dd = h2 * sgn[t];
    #pragma unroll
    for (int i = 32; i >= 1; i >>= 1) { nn += __shfl_xor(nn, i, 64); dd += __shfl_xor(dd, i, 64); }
    if (lane == 0) { rn[wave] = nn; rd[wave] = dd; }
    __syncthreads();
    if (t == 0) {
        float n2 = rn[0] + rn[1] + rn[2] + rn[3];
        float dt = rd[0] + rd[1] + rd[2] + rd[3];
        outv[row] = dt / fmaxf(sqrtf(n2), 1e-12f);
    }
}

extern "C" void kernel_launch(void* const* d_in, const int* in_sizes, int n_in,
                              void* d_out, int out_size, void* d_ws, size_t ws_size,
                              hipStream_t stream)
{
    const int*   query    = (const int*)d_in[0];
    const int*   support  = (const int*)d_in[1];
    const int*   q_l_conn = (const int*)d_in[2];
    const int*   q_r_conn = (const int*)d_in[4];
    const int*   s_l_conn = (const int*)d_in[6];
    const int*   s_r_conn = (const int*)d_in[8];
    const float* emb      = (const float*)d_in[10];
    const float* gcn_W    = (const float*)d_in[11];
    const float* gcn_bias = (const float*)d_in[12];
    const float* gcn_b    = (const float*)d_in[13];
    const float* se_w1    = (const float*)d_in[14];
    const float* se_b1    = (const float*)d_in[15];
    const float* se_w2    = (const float*)d_in[16];
    const float* se_b2    = (const float*)d_in[17];
    const float* ln_g     = (const float*)d_in[18];
    const float* ln_b     = (const float*)d_in[19];
    const float* W_ih     = (const float*)d_in[20];
    const float* W_hh     = (const float*)d_in[21];
    const float* b_ih     = (const float*)d_in[22];
    const float* b_hh     = (const float*)d_in[23];
    float* out = (float*)d_out;

    float* ws     = (float*)d_ws;
    float* qn2    = ws;                    // 1088*256 f
    float* yq     = qn2    + 1088 * 256;   // 1088*256 f
    float* qg2    = yq     + 1088 * 256;   // 1088*256 f
    float* sg0    = qg2    + 1088 * 256;   // 256
    float* sgn    = sg0    + 256;          // 256
    float* gates  = sgn    + 256;          // 1024*1024 f
    float* c1     = gates  + 1024 * 1024;  // 1024*256 f
    float* avgbuf = c1     + 1024 * 256;   // 2112*256 f
    float* bias_c = avgbuf + 2112 * 256;   // 1024 f
    unsigned short* qn2b = (unsigned short*)(bias_c + 1024);  // 1088*256 sh
    unsigned short* h1b  = qn2b + 1088 * 256;                 // 1088*512 sh
    unsigned short* qg2b = h1b  + 1088 * 512;                 // 1024*256 sh
    unsigned short* hrb  = qg2b + 1024 * 256;                 // 1024*512 sh
    unsigned short* w1b  = hrb  + 1024 * 512;                 // 512*256 sh
    unsigned short* w2b  = w1b  + 512 * 256;                  // 256*512 sh
    unsigned short* wihb = w2b  + 256 * 512;                  // 1024*256 sh
    unsigned short* whhb = wihb + 1024 * 256;                 // 1024*512 sh
    float* sims = gates;   // overlay: sims (411.6k f) dies before gates written

    // 0. weight conversion (independent; fills pipeline head)
    convert_kernel<<<4100, 256, 0, stream>>>(
        se_w1, se_w2, W_ih, W_hh, b_ih, b_hh, w1b, w2b, wihb, whhb, bias_c);

    // 1. sims (barrier-free max-MLP gather, fp32 table — selection-exact)
    const int nwaves = NROW * NSLC;                       // 26754
    sims_kernel<<<(nwaves + 3) / 4, 256, 0, stream>>>(
        query, support, q_l_conn, q_r_conn, s_l_conn, s_r_conn, emb, sims);

    // 2. top-K rank + mean gather -> avgbuf
    rank_avg_kernel<<<NROW, 256, 0, stream>>>(
        query, support, q_l_conn, q_r_conn, s_l_conn, s_r_conn,
        emb, sims, avgbuf);

    // 3. GCN matvec GEMM -> qn2 (f32 + bf16)
    gcn_gemm_kernel<<<dim3(2, 33), 256, 0, stream>>>(
        avgbuf, gcn_W, gcn_bias, gcn_b, qn2, qn2b);

    // 4. SE GEMM1 (MFMA): h1_bf = bf16(relu(qn2 @ w1^T + b1))
    mfma_gemm<true, false, true><<<dim3(8, 17), 256, 0, stream>>>(
        qn2b, w1b, se_b1, nullptr, nullptr, h1b, 512, 256);

    // 5. SE GEMM2 (MFMA): yq = h1 @ w2^T + b2 + qn2
    mfma_gemm<false, true, true><<<dim3(4, 17), 256, 0, stream>>>(
        h1b, w2b, se_b2, qn2, yq, nullptr, 256, 512);

    // 6. LayerNorm -> qg2 (f32 + bf16) (+ support mean + l2norm in block 1024)
    ln_kernel<<<1025, 256, 0, stream>>>(yq, ln_g, ln_b, qg2, qg2b, sg0, sgn);

    // 7. gates = qg2 @ W_ih'^T + (b_ih+b_hh)  (MFMA, gate-compacted)
    mfma_gemm<false, false, true><<<dim3(16, 16), 256, 0, stream>>>(
        qg2b, wihb, bias_c, nullptr, gates, nullptr, 1024, 256);

    // 8. LSTM step 1 (c0=0, h_r0=0) -> c1, hr_bf
    lstm_step1_kernel<<<1024, 256, 0, stream>>>(gates, qg2, sg0, c1, hrb);

    // 9. gates += hr @ W_hh'^T  (MFMA, in-place add)
    mfma_gemm<false, true, false><<<dim3(16, 16), 256, 0, stream>>>(
        hrb, whhb, nullptr, gates, gates, nullptr, 1024, 512);

    // 10. LSTM step 2 + l2norm + dot(support_gn)
    lstm_step2_kernel<<<1024, 256, 0, stream>>>(gates, c1, qg2, sgn, out);
}